// Round 8
// baseline (413.724 us; speedup 1.0000x reference)
//
#include <hip/hip_runtime.h>
#include <hip/hip_fp16.h>

// cosFormer linear attention, MI355X. L=S=2048, B=4, E=1024.
// Pipeline: f32->f16 convert; 3 proj GEMMs (fp16 MFMA, fp32 acc, epilogue folds
// bias/relu/sin-cos concat); LDS-tiled transposes; k_sum + z reductions;
// kv GEMM; attn GEMM (epilogue * z) -> f32 out.
// R1: fused launches (15 -> 8 dispatches).
// R2: XCD swizzle: FETCH 204->49 MB (ideal) but latency-bound, 115us.
// R3: runtime-offset dbuf REGRESSED (alias-conservative vmcnt(0) before ds_reads).
// R5: static dbuf NEUTRAL (118us): depth-1 + full-drain can't cover HBM latency.
// R7: counted-vmcnt depth-2 (T3+T4), 256x128, 96KB LDS: 118->103us, MfmaUtil 20%.
//     Still ~1950cy stall/step: 1 block/CU -> one barrier group -> vmcnt waits
//     stall the whole CU; no independent waves to feed the matrix pipe.
// R8: SAME schedule, tile 128x128 BK=32, 4 waves, 4x16KB static buffers =
//     64KB LDS -> 2 blocks/CU (launch_bounds(256,2); VGPR ~152 -> 8 waves/CU).
//     Two independent barrier groups/CU: block A's vmcnt/barrier stall overlaps
//     block B's MFMAs (m114 mechanism) ON TOP of depth-2 counted prefetch.
//     Stage = 4 loads/wave -> steady 8 outstanding -> vmcnt(4).

typedef _Float16 f16;
typedef f16 f16x8 __attribute__((ext_vector_type(8)));
typedef f16 f16x4 __attribute__((ext_vector_type(4)));
typedef float f32x4 __attribute__((ext_vector_type(4)));

#define AS1 __attribute__((address_space(1)))
#define AS3 __attribute__((address_space(3)))

__device__ __forceinline__ void gload_lds16(const void* g, void* l) {
  // async global->LDS, 16B/lane; LDS dest = wave-uniform base + lane*16
  __builtin_amdgcn_global_load_lds((const AS1 void*)g, (AS3 void*)l, 16, 0, 0);
}

// XCD-chunked bijective swizzle (T1). Requires nwg % 8 == 0 (all our grids).
__device__ __forceinline__ void xcd_swz(int& bx, int& by, int& bz) {
  const int nx = gridDim.x, ny = gridDim.y;
  const int p = blockIdx.x + nx * (blockIdx.y + ny * blockIdx.z);
  const int chunk = (nx * ny * gridDim.z) >> 3;
  const int l = (p & 7) * chunk + (p >> 3);
  bx = l % nx;
  by = (l / nx) % ny;
  bz = l / (nx * ny);
}

// ---------------------------------------------------------------------------
// f32 -> f16 convert (vectorized x4); z selects one of three src/dst pairs
__global__ void cvt3(const float* __restrict__ s0, const float* __restrict__ s1,
                     const float* __restrict__ s2, f16* __restrict__ d0,
                     f16* __restrict__ d1, f16* __restrict__ d2, int n4) {
  const int z = blockIdx.z;
  const float* s = (z == 0) ? s0 : (z == 1) ? s1 : s2;
  f16* d = (z == 0) ? d0 : (z == 1) ? d1 : d2;
  const int i = blockIdx.x * 256 + threadIdx.x;
  if (i >= n4) return;
  const float4 v = ((const float4*)s)[i];
  f16x4 o = { (f16)v.x, (f16)v.y, (f16)v.z, (f16)v.w };
  ((f16x4*)d)[i] = o;
}

// ---------------------------------------------------------------------------
// Depth-2 counted-vmcnt pipelined 128x128x(BK=32) fp16 MFMA core, 4 waves.
//   acc[m][n] += sum_k A[m][k] * B[n][k]   (both operands k-contiguous)
// LDS per buffer: A = 8 blocks, B = 8 blocks of 1KB (16 rows x 32 k);
// block mt: lane l's 16B = row mt*16+(l&15), k quad*8..+7 -> ds_read_b128 at
// blockbase + lane*16 is conflict-free (counter-verified 0 on this layout).
// Wave w stages A blocks {w, 4+w} and B blocks {w, 4+w} (4 gloads/stage).
// Steady state: 2 stages (8 loads/wave) in flight; vmcnt(4) retires oldest;
// s_barrier makes the retire cross-wave; sched_barrier(0) pins ds_reads below.
__device__ __forceinline__ void mm_core(const f16* __restrict__ A, int lda,
                                        const f16* __restrict__ B, int ldb,
                                        int K, int m0, int n0,
                                        f16* As0, f16* Bs0, f16* As1, f16* Bs1,
                                        f16* As2, f16* Bs2, f16* As3, f16* Bs3,
                                        f32x4 (&acc)[4][4]) {
  const int tid  = threadIdx.x;
  const int lane = tid & 63;
  const int w    = tid >> 6;        // wave 0..3
  const int wm   = w >> 1, wn = w & 1;
  const int l15  = lane & 15;
  const int quad = lane >> 4;

  const f16* pa0 = A + (long)(m0 + w * 16 + l15) * lda + quad * 8;        // A block w
  const f16* pa1 = A + (long)(m0 + (4 + w) * 16 + l15) * lda + quad * 8;  // A block 4+w
  const f16* pb0 = B + (long)(n0 + w * 16 + l15) * ldb + quad * 8;        // B block w
  const f16* pb1 = B + (long)(n0 + (4 + w) * 16 + l15) * ldb + quad * 8;  // B block 4+w
  int koff = 0;

#define STAGE_(Ab, Bb) do {                        \
    gload_lds16(pa0 + koff, (Ab) + w * 512);       \
    gload_lds16(pa1 + koff, (Ab) + (4 + w) * 512); \
    gload_lds16(pb0 + koff, (Bb) + w * 512);       \
    gload_lds16(pb1 + koff, (Bb) + (4 + w) * 512); \
    koff += 32; } while (0)

#define COMPUTE_(Ab, Bb) do {                                                    \
    f16x8 af[4], bf[4];                                                          \
    _Pragma("unroll")                                                            \
    for (int i = 0; i < 4; ++i)                                                  \
      af[i] = *(const f16x8*)((Ab) + (wm * 4 + i) * 512 + lane * 8);             \
    _Pragma("unroll")                                                            \
    for (int j = 0; j < 4; ++j)                                                  \
      bf[j] = *(const f16x8*)((Bb) + (wn * 4 + j) * 512 + lane * 8);             \
    _Pragma("unroll")                                                            \
    for (int i = 0; i < 4; ++i)                                                  \
      _Pragma("unroll")                                                          \
      for (int j = 0; j < 4; ++j)                                                \
        acc[i][j] = __builtin_amdgcn_mfma_f32_16x16x32_f16(af[i], bf[j],         \
                                                           acc[i][j], 0, 0, 0); \
  } while (0)

#define WV4_ asm volatile("s_waitcnt vmcnt(4)" ::: "memory")
#define WV0_ asm volatile("s_waitcnt vmcnt(0)" ::: "memory")
#define BARR_ do { __builtin_amdgcn_s_barrier(); __builtin_amdgcn_sched_barrier(0); } while (0)

  // prologue: 2 stages in flight (8 loads/wave)
  STAGE_(As0, Bs0);
  STAGE_(As1, Bs1);

  const int nt = K >> 5;            // 32 (K=1024) or 64 (K=2048); nt % 4 == 0
  for (int t = 0; t + 5 < nt; t += 4) {
    WV4_; BARR_; STAGE_(As2, Bs2); COMPUTE_(As0, Bs0);
    WV4_; BARR_; STAGE_(As3, Bs3); COMPUTE_(As1, Bs1);
    WV4_; BARR_; STAGE_(As0, Bs0); COMPUTE_(As2, Bs2);
    WV4_; BARR_; STAGE_(As1, Bs1); COMPUTE_(As3, Bs3);
  }
  // peeled final 4 sub-steps (t == nt-4): stages nt-2, nt-1 then drain
  WV4_; BARR_; STAGE_(As2, Bs2); COMPUTE_(As0, Bs0);
  WV4_; BARR_; STAGE_(As3, Bs3); COMPUTE_(As1, Bs1);
  WV4_; BARR_; COMPUTE_(As2, Bs2);   // 8 outstanding -> retires stage(nt-2)
  WV0_; BARR_; COMPUTE_(As3, Bs3);   // 4 outstanding -> full drain

#undef STAGE_
#undef COMPUTE_
#undef WV4_
#undef WV0_
#undef BARR_
}

#define GEMM_LDS                                   \
  __shared__ alignas(16) f16 As0[4096];            \
  __shared__ alignas(16) f16 Bs0[4096];            \
  __shared__ alignas(16) f16 As1[4096];            \
  __shared__ alignas(16) f16 Bs1[4096];            \
  __shared__ alignas(16) f16 As2[4096];            \
  __shared__ alignas(16) f16 Bs2[4096];            \
  __shared__ alignas(16) f16 As3[4096];            \
  __shared__ alignas(16) f16 Bs3[4096];

// ---------------------------------------------------------------------------
// Fused Q/K/V projection GEMM. grid = (8, 64, 3), 256 thr; z selects set.
// z=0: Q -> Qf (relu+bias, sin/cos dual write, ldc=2048)
// z=1: K -> Kn (same)
// z=2: V -> Vp (bias only, ldc=1024)
__launch_bounds__(256, 2)
__global__ void proj_gemm(const f16* __restrict__ q16, const f16* __restrict__ k16,
                          const f16* __restrict__ v16, const f16* __restrict__ wq,
                          const f16* __restrict__ wk, const f16* __restrict__ wv,
                          const float* __restrict__ bq, const float* __restrict__ bk,
                          const float* __restrict__ bv,
                          f16* __restrict__ Qf, f16* __restrict__ Kn, f16* __restrict__ Vp) {
  GEMM_LDS
  int bx, by, z;
  xcd_swz(bx, by, z);
  const f16* A = (z == 0) ? q16 : (z == 1) ? k16 : v16;
  const f16* B = (z == 0) ? wq : (z == 1) ? wk : wv;
  const float* bias = (z == 0) ? bq : (z == 1) ? bk : bv;
  const int m0 = by * 128;
  const int n0 = bx * 128;

  f32x4 acc[4][4] = {};
  mm_core(A, 1024, B, 1024, 1024, m0, n0,
          As0, Bs0, As1, Bs1, As2, Bs2, As3, Bs3, acc);

  const int tid  = threadIdx.x;
  const int lane = tid & 63;
  const int w    = tid >> 6;
  const int wm   = w >> 1, wn = w & 1;
  const int l15  = lane & 15;
  const int quad = lane >> 4;

  // C/D layout (verified m89/m91): col = lane&15, row = quad*4 + reg.
  if (z < 2) {
    f16* C = (z == 0) ? Qf : Kn;
    const int ldc = 2048, halfw = 1024;
#pragma unroll
    for (int i = 0; i < 4; ++i) {
      const int mg = m0 + wm * 64 + i * 16 + quad * 4;
      float sn[4], cn[4];
#pragma unroll
      for (int rr = 0; rr < 4; ++rr) {
        const int l = (mg + rr) >> 2;          // natural row = l*4 + b
        const float ang = 7.6699039394282066e-4f * (float)(l + 1);  // (pi/2)/2048 * (l+1)
        __sincosf(ang, &sn[rr], &cn[rr]);
      }
#pragma unroll
      for (int j = 0; j < 4; ++j) {
        const int ng = n0 + wn * 64 + j * 16 + l15;
        const float bc = bias[ng];
#pragma unroll
        for (int rr = 0; rr < 4; ++rr) {
          const float v = fmaxf(acc[i][j][rr] + bc, 0.f);
          C[(long)(mg + rr) * ldc + ng]         = (f16)(v * sn[rr]);
          C[(long)(mg + rr) * ldc + ng + halfw] = (f16)(v * cn[rr]);
        }
      }
    }
  } else {
    f16* C = Vp;
    const int ldc = 1024;
#pragma unroll
    for (int i = 0; i < 4; ++i) {
      const int mg = m0 + wm * 64 + i * 16 + quad * 4;
#pragma unroll
      for (int j = 0; j < 4; ++j) {
        const int ng = n0 + wn * 64 + j * 16 + l15;
        const float bc = bias[ng];
#pragma unroll
        for (int rr = 0; rr < 4; ++rr)
          C[(long)(mg + rr) * ldc + ng] = (f16)(acc[i][j][rr] + bc);
      }
    }
  }
}

// ---------------------------------------------------------------------------
// Generic GEMM (kv and attn stages), 256 thr, BM=128/BN=128.
// MODE 2: kv   -> f16 C = acc
// MODE 3: attn -> f32 C = acc * z[l*4+bz]
template<int MODE>
__launch_bounds__(256, 2)
__global__ void gemm_bt(const f16* __restrict__ A, int lda,
                        const f16* __restrict__ B, int ldb,
                        void* __restrict__ Cout, int K, int ldc,
                        const float* __restrict__ zvec,
                        long abatch, long bbatch, long cbatch)
{
  GEMM_LDS
  int bx, by, bz;
  xcd_swz(bx, by, bz);
  A += (long)bz * abatch;
  B += (long)bz * bbatch;
  const int m0 = by * 128;
  const int n0 = bx * 128;

  f32x4 acc[4][4] = {};
  mm_core(A, lda, B, ldb, K, m0, n0,
          As0, Bs0, As1, Bs1, As2, Bs2, As3, Bs3, acc);

  const int tid  = threadIdx.x;
  const int lane = tid & 63;
  const int w    = tid >> 6;
  const int wm   = w >> 1, wn = w & 1;
  const int l15  = lane & 15;
  const int quad = lane >> 4;

  if constexpr (MODE == 2) {
    f16* C = (f16*)Cout + (long)bz * cbatch;
#pragma unroll
    for (int i = 0; i < 4; ++i) {
      const int mg = m0 + wm * 64 + i * 16 + quad * 4;
#pragma unroll
      for (int j = 0; j < 4; ++j) {
        const int ng = n0 + wn * 64 + j * 16 + l15;
#pragma unroll
        for (int rr = 0; rr < 4; ++rr)
          C[(long)(mg + rr) * ldc + ng] = (f16)acc[i][j][rr];
      }
    }
  } else {  // MODE 3: attn, f32 out, scale by z
    float* C = (float*)Cout + (long)bz * cbatch;
#pragma unroll
    for (int i = 0; i < 4; ++i) {
      const int mg = m0 + wm * 64 + i * 16 + quad * 4;
      float zr[4];
#pragma unroll
      for (int rr = 0; rr < 4; ++rr) zr[rr] = zvec[(long)(mg + rr) * 4 + bz];
#pragma unroll
      for (int j = 0; j < 4; ++j) {
        const int ng = n0 + wn * 64 + j * 16 + l15;
#pragma unroll
        for (int rr = 0; rr < 4; ++rr)
          C[(long)(mg + rr) * ldc + ng] = acc[i][j][rr] * zr[rr];
      }
    }
  }
}

// ---------------------------------------------------------------------------
// fp16 64x64 LDS-tiled transpose, K and V fused in one launch.
// grid = (32, 32, 8): z<4 -> K batch z; z>=4 -> V batch z-4 (x<16 only).
__global__ void transpose_fused(const f16* __restrict__ Kn, f16* __restrict__ Kt,
                                const f16* __restrict__ Vp, f16* __restrict__ Vt) {
  __shared__ f16 tile[64 * 72];   // +8 halves pad (144B stride keeps 16B alignment)
  const int z = blockIdx.z;
  const f16* in;
  f16* out;
  long in_batch, out_batch;
  int ldin, ldout, b;
  if (z < 4) {
    in = Kn; out = Kt; in_batch = 2048; out_batch = 2048L * 2048;
    ldin = 8192; ldout = 2048; b = z;
  } else {
    if (blockIdx.x >= 16) return;   // V col dim is 1024 (uniform exit, pre-barrier)
    in = Vp; out = Vt; in_batch = 1024; out_batch = 1024L * 2048;
    ldin = 4096; ldout = 2048; b = z - 4;
  }
  in  += (long)b * in_batch;
  out += (long)b * out_batch;
  const int r0 = blockIdx.y * 64;
  const int c0 = blockIdx.x * 64;
  const int t  = threadIdx.x;
  {
    const int r = t >> 2, cs = (t & 3) * 16;
    const f16* src = in + (long)(r0 + r) * ldin + c0 + cs;
    f16x8 v0 = *(const f16x8*)(src);
    f16x8 v1 = *(const f16x8*)(src + 8);
    *(f16x8*)(tile + r * 72 + cs)     = v0;
    *(f16x8*)(tile + r * 72 + cs + 8) = v1;
  }
  __syncthreads();
  {
    const int c = t >> 2, rs = (t & 3) * 16;
    alignas(16) f16 tmp[16];
#pragma unroll
    for (int j = 0; j < 16; ++j) tmp[j] = tile[(rs + j) * 72 + c];
    f16* dst = out + (long)(c0 + c) * ldout + r0 + rs;
    *(f16x8*)(dst)     = *(const f16x8*)(tmp);
    *(f16x8*)(dst + 8) = *(const f16x8*)(tmp + 8);
  }
}

// ---------------------------------------------------------------------------
// k_sum[b][d] = sum_s K_t[b][d][s]  (one block per row of 2048)
__global__ void ksum_kernel(const f16* __restrict__ Kt, float* __restrict__ ks) {
  const long row = blockIdx.x;
  const int t = threadIdx.x;
  f16x8 v = *(const f16x8*)(Kt + row * 2048 + t * 8);
  float s = 0.f;
#pragma unroll
  for (int j = 0; j < 8; ++j) s += (float)v[j];
#pragma unroll
  for (int off = 32; off > 0; off >>= 1) s += __shfl_down(s, off, 64);
  __shared__ float red[4];
  if ((t & 63) == 0) red[t >> 6] = s;
  __syncthreads();
  if (t == 0) ks[row] = red[0] + red[1] + red[2] + red[3];
}

// z[r=l*4+b] = 1 / max(sum_d Q_[r][d] * k_sum[b][d], eps)
__global__ void z_kernel(const f16* __restrict__ Qf, const float* __restrict__ ks,
                         float* __restrict__ zb) {
  const long r = blockIdx.x;
  const int t = threadIdx.x;
  const int b = (int)(r & 3);
  f16x8 q = *(const f16x8*)(Qf + r * 2048 + t * 8);
  const float* kp = ks + b * 2048 + t * 8;
  float s = 0.f;
#pragma unroll
  for (int j = 0; j < 8; ++j) s += (float)q[j] * kp[j];
#pragma unroll
  for (int off = 32; off > 0; off >>= 1) s += __shfl_down(s, off, 64);
  __shared__ float red[4];
  if ((t & 63) == 0) red[t >> 6] = s;
  __syncthreads();
  if (t == 0) zb[r] = 1.f / fmaxf(red[0] + red[1] + red[2] + red[3], 1e-6f);
}

// ---------------------------------------------------------------------------
extern "C" void kernel_launch(void* const* d_in, const int* in_sizes, int n_in,
                              void* d_out, int out_size, void* d_ws, size_t ws_size,
                              hipStream_t stream) {
  const float* query = (const float*)d_in[0];
  const float* key_  = (const float*)d_in[1];
  const float* value = (const float*)d_in[2];
  const float* Wq    = (const float*)d_in[3];
  const float* bq    = (const float*)d_in[4];
  const float* Wk    = (const float*)d_in[5];
  const float* bk    = (const float*)d_in[6];
  const float* Wv    = (const float*)d_in[7];
  const float* bv    = (const float*)d_in[8];

  char* ws = (char*)d_ws;
  const size_t MB = 1ull << 20;
  // Workspace layout (peak 134 MB, with lifetime-based aliasing):
  f16* wq16 = (f16*)(ws + 0 * MB);    // 2 MB
  f16* wk16 = (f16*)(ws + 2 * MB);    // 2 MB
  f16* wv16 = (f16*)(ws + 4 * MB);    // 2 MB
  f16* q16  = (f16*)(ws + 6 * MB);    // 16 MB (dead after proj GEMMs)
  f16* k16  = (f16*)(ws + 22 * MB);   // 16 MB (dead after proj GEMMs)
  f16* v16  = (f16*)(ws + 38 * MB);   // 16 MB (dead after proj GEMMs)
  f16* Qf   = (f16*)(ws + 54 * MB);   // 32 MB  Q_ [l*4+b][2048]
  f16* Kn   = (f16*)(ws + 86 * MB);   // 32 MB  K_ natural [s*4+b][2048] (dead after transpose)
  f16* Vp   = (f16*)(ws + 118 * MB);  // 16 MB  V  natural [s*4+b][1024] (dead after transpose)
  f16* Kt   = (f16*)(ws + 6 * MB);    // 32 MB  K_t [b][d][s]   (aliases q16+k16)
  f16* Vt   = (f16*)(ws + 38 * MB);   // 16 MB  V_t [b][m][s]   (aliases v16)
  f16* kvb  = (f16*)(ws + 86 * MB);   // 16 MB  kv  [b][m][d]   (aliases Kn)
  float* ks = (float*)(ws + 102 * MB);  // 32 KB k_sum[b][d]
  float* zb = (float*)(ws + 103 * MB);  // 32 KB z[l*4+b]

  // 1) f32 -> f16 (2 fused launches)
  cvt3<<<dim3(8192, 1, 3), 256, 0, stream>>>(query, key_, value, q16, k16, v16, 2097152);
  cvt3<<<dim3(1024, 1, 3), 256, 0, stream>>>(Wq, Wk, Wv, wq16, wk16, wv16, 262144);

  // 2) projections fused (M=8192, N=1024, K=1024; z selects Q/K/V); 1536 blocks
  proj_gemm<<<dim3(8, 64, 3), 256, 0, stream>>>(q16, k16, v16, wq16, wk16, wv16,
                                                bq, bk, bv, Qf, Kn, Vp);

  // 3) transposes fused: K_ [s][d] -> K_t [d][s]; V [s][m] -> V_t [m][s]
  transpose_fused<<<dim3(32, 32, 8), 256, 0, stream>>>(Kn, Kt, Vp, Vt);

  // 4) k_sum and z
  ksum_kernel<<<8192, 256, 0, stream>>>(Kt, ks);
  z_kernel<<<8192, 256, 0, stream>>>(Qf, ks, zb);

  // 5) kv[b][m][d] = sum_s V_t[m][s] * K_t[d][s]  (M=1024, N=2048, K=2048); 512 blocks
  gemm_bt<2><<<dim3(16, 8, 4), 256, 0, stream>>>(Vt, 2048, Kt, 2048, kvb, 2048, 2048,
                                                 nullptr, 1024L * 2048, 2048L * 2048, 1024L * 2048);
  // 6) attn[l][b][m] = z * sum_d Q_[l][d] * kv[m][d]  (M=2048, N=1024, K=2048); 512 blocks
  gemm_bt<3><<<dim3(8, 16, 4), 256, 0, stream>>>(Qf, 8192, kvb, 2048, d_out, 2048, 4096,
                                                 zb, 2048, 1024L * 2048, 1024);
}

// Round 12
// 379.178 us; speedup vs baseline: 1.0911x; 1.0911x over previous
//
#include <hip/hip_runtime.h>
#include <hip/hip_fp16.h>

// cosFormer linear attention, MI355X. L=S=2048, B=4, E=1024.
// R1: fused launches. R2: XCD swizzle (FETCH 204->49MB = ideal). R3: runtime
// dbuf regressed (alias-conservative vmcnt0). R5: static dbuf neutral.
// R7: counted-vmcnt depth-2 256x128: best wall 372.7us, proj 103us, Mfma 20%.
// R8: 128sq 2-block/CU: regressed. Conclusion: coarse stage->compute phases cap
// this family at ~500 TF (m233: critical path = stage+vmcnt+barrier).
// R9: fine-phase port for PROJ (kv/attn keep R7 structure verbatim):
//   256x256, BK=64, 512thr/8 waves, 2x64KB static dbuf (128KB).
//   4 phases/K-tile: {vmcnt(4); s_barrier; stage ONE half of tile t+1
//   (2 gloads); 12 ds_read_b128; setprio1; 16 MFMA; setprio0}.
//   Wave output = 4 SCATTERED 64x32 quadrants: phase (qm,qn) needs exactly
//   halves (Ah_qm, Bh_qn) -> stage order Ah0,Bh0,Bh1,Ah1 gives every half
//   >=3-phase lead; per-wave gates provably vmcnt(4)/(4)/(4)/none
//   (last tile 4/2/0/none). LDS fragment-blocked = conflict-free (T2 by
//   construction); T3+T4 counted pipeline; T5 setprio.
// R10-R12: resubmissions (rounds 9-11 hit GPU-acquisition timeouts).

typedef _Float16 f16;
typedef f16 f16x8 __attribute__((ext_vector_type(8)));
typedef f16 f16x4 __attribute__((ext_vector_type(4)));
typedef float f32x4 __attribute__((ext_vector_type(4)));

#define AS1 __attribute__((address_space(1)))
#define AS3 __attribute__((address_space(3)))

__device__ __forceinline__ void gload_lds16(const void* g, void* l) {
  // async global->LDS, 16B/lane; LDS dest = wave-uniform base + lane*16
  __builtin_amdgcn_global_load_lds((const AS1 void*)g, (AS3 void*)l, 16, 0, 0);
}

// XCD-chunked bijective swizzle (T1). Requires nwg % 8 == 0 (all our grids).
__device__ __forceinline__ void xcd_swz(int& bx, int& by, int& bz) {
  const int nx = gridDim.x, ny = gridDim.y;
  const int p = blockIdx.x + nx * (blockIdx.y + ny * blockIdx.z);
  const int chunk = (nx * ny * gridDim.z) >> 3;
  const int l = (p & 7) * chunk + (p >> 3);
  bx = l % nx;
  by = (l / nx) % ny;
  bz = l / (nx * ny);
}

// ---------------------------------------------------------------------------
// f32 -> f16 convert (vectorized x4); z selects one of three src/dst pairs
__global__ void cvt3(const float* __restrict__ s0, const float* __restrict__ s1,
                     const float* __restrict__ s2, f16* __restrict__ d0,
                     f16* __restrict__ d1, f16* __restrict__ d2, int n4) {
  const int z = blockIdx.z;
  const float* s = (z == 0) ? s0 : (z == 1) ? s1 : s2;
  f16* d = (z == 0) ? d0 : (z == 1) ? d1 : d2;
  const int i = blockIdx.x * 256 + threadIdx.x;
  if (i >= n4) return;
  const float4 v = ((const float4*)s)[i];
  f16x4 o = { (f16)v.x, (f16)v.y, (f16)v.z, (f16)v.w };
  ((f16x4*)d)[i] = o;
}

// ---------------------------------------------------------------------------
// Fused Q/K/V projection GEMM, fine-phase 256x256 core. grid=(4,32,3), 512thr.
// z=0: Q -> Qf (relu+bias, sin/cos dual write, ldc=2048)
// z=1: K -> Kn (same)   z=2: V -> Vp (bias only, ldc=1024)
// LDS per buffer: A-tile 256x64 as 32 fragment-blocks of 1KB (bid=mt*2+kt;
// lane l: row mt*16+(l&15), k kt*32+(l>>4)*8..+7); B-tile same by ntile.
// Halves: Ah0 = mt0..7, Ah1 = mt8..15; Bh0 = ntile0..7, Bh1 = 8..15.
// Wave w (wm=w>>2, wn=w&3): quadrant (qm,qn) = rows qm*128+wm*64..+64,
// cols qn*128+wn*32..+32  ->  phase (qm,qn) touches exactly (Ah_qm, Bh_qn).
__launch_bounds__(512, 2)
__global__ void proj_gemm(const f16* __restrict__ q16, const f16* __restrict__ k16,
                          const f16* __restrict__ v16, const f16* __restrict__ wq,
                          const f16* __restrict__ wk, const f16* __restrict__ wv,
                          const float* __restrict__ bq, const float* __restrict__ bk,
                          const float* __restrict__ bv,
                          f16* __restrict__ Qf, f16* __restrict__ Kn, f16* __restrict__ Vp) {
  __shared__ alignas(16) f16 As0[16384];   // 32 KB
  __shared__ alignas(16) f16 Bs0[16384];
  __shared__ alignas(16) f16 As1[16384];
  __shared__ alignas(16) f16 Bs1[16384];

  int bx, by, z;
  xcd_swz(bx, by, z);
  const f16* A = (z == 0) ? q16 : (z == 1) ? k16 : v16;
  const f16* B = (z == 0) ? wq : (z == 1) ? wk : wv;
  const float* bias = (z == 0) ? bq : (z == 1) ? bk : bv;
  const int m0 = by * 256;
  const int n0 = bx * 256;

  const int tid  = threadIdx.x;
  const int lane = tid & 63;
  const int w    = tid >> 6;        // 0..7
  const int wm   = w >> 2;          // 0..1
  const int wn   = w & 3;           // 0..3
  const int l15  = lane & 15;
  const int quad = lane >> 4;
  const int lda = 1024, ldb = 1024, K = 1024;

  // staging pointers (wave w's share: mt=w / 8+w, ntile=w / 8+w)
  const f16* gA0 = A + (long)(m0 + w * 16 + l15) * lda + quad * 8;
  const f16* gA1 = gA0 + 128 * lda;
  const f16* gB0 = B + (long)(n0 + w * 16 + l15) * ldb + quad * 8;
  const f16* gB1 = gB0 + 128 * ldb;
  int ko = 0;

  f32x4 acc[4][4][2] = {};          // [quadrant][mi][nj], all literal-indexed
  f16x8 af[4][2], bf[2][2];

#define ST_AH0(AW) do { gload_lds16(gA0 + ko, (AW) + w * 1024); \
                        gload_lds16(gA0 + ko + 32, (AW) + w * 1024 + 512); } while (0)
#define ST_AH1(AW) do { gload_lds16(gA1 + ko, (AW) + (8 + w) * 1024); \
                        gload_lds16(gA1 + ko + 32, (AW) + (8 + w) * 1024 + 512); } while (0)
#define ST_BH0(BW) do { gload_lds16(gB0 + ko, (BW) + w * 1024); \
                        gload_lds16(gB0 + ko + 32, (BW) + w * 1024 + 512); } while (0)
#define ST_BH1(BW) do { gload_lds16(gB1 + ko, (BW) + (8 + w) * 1024); \
                        gload_lds16(gB1 + ko + 32, (BW) + (8 + w) * 1024 + 512); } while (0)

  // af for m-half qm: mt = qm*8 + wm*4 + mi
#define RD_AF(AR, qm) do { _Pragma("unroll") \
    for (int mi = 0; mi < 4; ++mi) { _Pragma("unroll") \
      for (int kt = 0; kt < 2; ++kt) \
        af[mi][kt] = *(const f16x8*)((AR) + (((qm) * 8 + wm * 4 + mi) * 2 + kt) * 512 + lane * 8); } } while (0)
  // bf for n-half qn: ntile = qn*8 + wn*2 + nj
#define RD_BF(BR, qn) do { _Pragma("unroll") \
    for (int nj = 0; nj < 2; ++nj) { _Pragma("unroll") \
      for (int kt = 0; kt < 2; ++kt) \
        bf[nj][kt] = *(const f16x8*)((BR) + (((qn) * 8 + wn * 2 + nj) * 2 + kt) * 512 + lane * 8); } } while (0)

#define MF16(q) do { __builtin_amdgcn_s_setprio(1); _Pragma("unroll") \
    for (int mi = 0; mi < 4; ++mi) { _Pragma("unroll") \
      for (int nj = 0; nj < 2; ++nj) { _Pragma("unroll") \
        for (int kt = 0; kt < 2; ++kt) \
          acc[q][mi][nj] = __builtin_amdgcn_mfma_f32_16x16x32_f16(af[mi][kt], bf[nj][kt], acc[q][mi][nj], 0, 0, 0); } } \
    __builtin_amdgcn_s_setprio(0); } while (0)

#define WV4_ asm volatile("s_waitcnt vmcnt(4)" ::: "memory")
#define WV2_ asm volatile("s_waitcnt vmcnt(2)" ::: "memory")
#define WV0_ asm volatile("s_waitcnt vmcnt(0)" ::: "memory")
#define BARR_ do { __builtin_amdgcn_s_barrier(); __builtin_amdgcn_sched_barrier(0); } while (0)

  // quadrant order: q0=(0,0), q1=(0,1), q2=(1,1), q3=(1,0)
  // phase needs:    ph1: Ah0,Bh0  ph2: Bh1  ph3: Ah1  ph4: (reuse)
  // stage order (tile t+1): ph1: Ah0  ph2: Bh0  ph3: Bh1  ph4: Ah1
#define TILE(AR, BR, AW, BW) do {                                  \
    WV4_; BARR_; ST_AH0(AW); RD_AF(AR, 0); RD_BF(BR, 0); MF16(0);  \
    WV4_; BARR_; ST_BH0(BW); RD_BF(BR, 1); MF16(1);                \
    WV4_; BARR_; ST_BH1(BW); RD_AF(AR, 1); MF16(2);                \
          BARR_; ST_AH1(AW); RD_BF(BR, 0); MF16(3);                \
    ko += 64; } while (0)

#define TILE_LAST(AR, BR) do {                                     \
    WV4_; BARR_; RD_AF(AR, 0); RD_BF(BR, 0); MF16(0);              \
    WV2_; BARR_; RD_BF(BR, 1); MF16(1);                            \
    WV0_; BARR_; RD_AF(AR, 1); MF16(2);                            \
          BARR_; RD_BF(BR, 0); MF16(3); } while (0)

  // prologue: stage tile 0 fully (same half order), then uniform loop
  ST_AH0(As0); ST_BH0(Bs0); ST_BH1(Bs0); ST_AH1(As0);
  ko = 64;

  const int nt = K >> 6;            // 16
  for (int t = 0; t + 2 < nt; t += 2) {
    TILE(As0, Bs0, As1, Bs1);
    TILE(As1, Bs1, As0, Bs0);
  }
  TILE(As0, Bs0, As1, Bs1);         // tile nt-2 (stages tile nt-1)
  TILE_LAST(As1, Bs1);              // tile nt-1

#undef ST_AH0
#undef ST_AH1
#undef ST_BH0
#undef ST_BH1
#undef RD_AF
#undef RD_BF
#undef MF16
#undef WV4_
#undef WV2_
#undef WV0_
#undef BARR_
#undef TILE
#undef TILE_LAST

  // Epilogue. C/D layout (verified m89/m91): col = lane&15, row = quad*4 + reg.
  const int QM[4] = {0, 0, 1, 1};
  const int QN[4] = {0, 1, 1, 0};
  if (z < 2) {
    f16* C = (z == 0) ? Qf : Kn;
    const int ldc = 2048, halfw = 1024;
#pragma unroll
    for (int q = 0; q < 4; ++q) {
      const int rbase = m0 + QM[q] * 128 + wm * 64;
      const int cbase = n0 + QN[q] * 128 + wn * 32;
#pragma unroll
      for (int mi = 0; mi < 4; ++mi) {
        const int mg = rbase + mi * 16 + quad * 4;
        float sn[4], cn[4];
#pragma unroll
        for (int rr = 0; rr < 4; ++rr) {
          const int l = (mg + rr) >> 2;          // natural row = l*4 + b
          const float ang = 7.6699039394282066e-4f * (float)(l + 1);  // (pi/2)/2048*(l+1)
          __sincosf(ang, &sn[rr], &cn[rr]);
        }
#pragma unroll
        for (int nj = 0; nj < 2; ++nj) {
          const int ng = cbase + nj * 16 + l15;
          const float bc = bias[ng];
#pragma unroll
          for (int rr = 0; rr < 4; ++rr) {
            const float v = fmaxf(acc[q][mi][nj][rr] + bc, 0.f);
            C[(long)(mg + rr) * ldc + ng]         = (f16)(v * sn[rr]);
            C[(long)(mg + rr) * ldc + ng + halfw] = (f16)(v * cn[rr]);
          }
        }
      }
    }
  } else {
    f16* C = Vp;
    const int ldc = 1024;
#pragma unroll
    for (int q = 0; q < 4; ++q) {
      const int rbase = m0 + QM[q] * 128 + wm * 64;
      const int cbase = n0 + QN[q] * 128 + wn * 32;
#pragma unroll
      for (int mi = 0; mi < 4; ++mi) {
        const int mg = rbase + mi * 16 + quad * 4;
#pragma unroll
        for (int nj = 0; nj < 2; ++nj) {
          const int ng = cbase + nj * 16 + l15;
          const float bc = bias[ng];
#pragma unroll
          for (int rr = 0; rr < 4; ++rr)
            C[(long)(mg + rr) * ldc + ng] = (f16)(acc[q][mi][nj][rr] + bc);
        }
      }
    }
  }
}

// ---------------------------------------------------------------------------
// R7 core (verbatim): depth-2 counted-vmcnt 256x128xBK32, 8 waves, 96KB LDS.
// Used for kv and attn stages (their best measured config).
__device__ __forceinline__ void mm_core_kva(const f16* __restrict__ A, int lda,
                                            const f16* __restrict__ B, int ldb,
                                            int K, int m0, int n0,
                                            f16* As0, f16* Bs0, f16* As1, f16* Bs1,
                                            f16* As2, f16* Bs2, f16* As3, f16* Bs3,
                                            f32x4 (&acc)[4][4]) {
  const int tid  = threadIdx.x;
  const int lane = tid & 63;
  const int w    = tid >> 6;        // wave 0..7
  const int wm   = w >> 1, wn = w & 1;
  const int l15  = lane & 15;
  const int quad = lane >> 4;

  const f16* pa0 = A + (long)(m0 + w * 16 + l15) * lda + quad * 8;        // A block w
  const f16* pa1 = A + (long)(m0 + (8 + w) * 16 + l15) * lda + quad * 8;  // A block 8+w
  const f16* pb0 = B + (long)(n0 + w * 16 + l15) * ldb + quad * 8;        // B block w
  int koff = 0;

#define STAGE_(Ab, Bb) do {                        \
    gload_lds16(pa0 + koff, (Ab) + w * 512);       \
    gload_lds16(pa1 + koff, (Ab) + (8 + w) * 512); \
    gload_lds16(pb0 + koff, (Bb) + w * 512);       \
    koff += 32; } while (0)

#define COMPUTE_(Ab, Bb) do {                                                    \
    f16x8 af[4], bf[4];                                                          \
    _Pragma("unroll")                                                            \
    for (int i = 0; i < 4; ++i)                                                  \
      af[i] = *(const f16x8*)((Ab) + (wm * 4 + i) * 512 + lane * 8);             \
    _Pragma("unroll")                                                            \
    for (int j = 0; j < 4; ++j)                                                  \
      bf[j] = *(const f16x8*)((Bb) + (wn * 4 + j) * 512 + lane * 8);             \
    _Pragma("unroll")                                                            \
    for (int i = 0; i < 4; ++i)                                                  \
      _Pragma("unroll")                                                          \
      for (int j = 0; j < 4; ++j)                                                \
        acc[i][j] = __builtin_amdgcn_mfma_f32_16x16x32_f16(af[i], bf[j],         \
                                                           acc[i][j], 0, 0, 0); \
  } while (0)

#define WV3_ asm volatile("s_waitcnt vmcnt(3)" ::: "memory")
#define WV0_ asm volatile("s_waitcnt vmcnt(0)" ::: "memory")
#define BARR_ do { __builtin_amdgcn_s_barrier(); __builtin_amdgcn_sched_barrier(0); } while (0)

  // prologue: 2 stages in flight
  STAGE_(As0, Bs0);
  STAGE_(As1, Bs1);

  const int nt = K >> 5;            // 64 for K=2048; nt % 4 == 0
  for (int t = 0; t + 5 < nt; t += 4) {
    WV3_; BARR_; STAGE_(As2, Bs2); COMPUTE_(As0, Bs0);
    WV3_; BARR_; STAGE_(As3, Bs3); COMPUTE_(As1, Bs1);
    WV3_; BARR_; STAGE_(As0, Bs0); COMPUTE_(As2, Bs2);
    WV3_; BARR_; STAGE_(As1, Bs1); COMPUTE_(As3, Bs3);
  }
  // peeled final 4 sub-steps
  WV3_; BARR_; STAGE_(As2, Bs2); COMPUTE_(As0, Bs0);
  WV3_; BARR_; STAGE_(As3, Bs3); COMPUTE_(As1, Bs1);
  WV3_; BARR_; COMPUTE_(As2, Bs2);
  WV0_; BARR_; COMPUTE_(As3, Bs3);

#undef STAGE_
#undef COMPUTE_
#undef WV3_
#undef WV0_
#undef BARR_
}

#define GEMM_LDS                                   \
  __shared__ alignas(16) f16 As0[8192];            \
  __shared__ alignas(16) f16 Bs0[4096];            \
  __shared__ alignas(16) f16 As1[8192];            \
  __shared__ alignas(16) f16 Bs1[4096];            \
  __shared__ alignas(16) f16 As2[8192];            \
  __shared__ alignas(16) f16 Bs2[4096];            \
  __shared__ alignas(16) f16 As3[8192];            \
  __shared__ alignas(16) f16 Bs3[4096];

// ---------------------------------------------------------------------------
// Generic GEMM (kv and attn stages), 512 thr, BM=256/BN=128 (R7 verbatim).
// MODE 2: kv   -> f16 C = acc
// MODE 3: attn -> f32 C = acc * z[l*4+bz]
template<int MODE>
__launch_bounds__(512, 2)
__global__ void gemm_bt(const f16* __restrict__ A, int lda,
                        const f16* __restrict__ B, int ldb,
                        void* __restrict__ Cout, int K, int ldc,
                        const float* __restrict__ zvec,
                        long abatch, long bbatch, long cbatch)
{
  GEMM_LDS
  int bx, by, bz;
  xcd_swz(bx, by, bz);
  A += (long)bz * abatch;
  B += (long)bz * bbatch;
  const int m0 = by * 256;
  const int n0 = bx * 128;

  f32x4 acc[4][4] = {};
  mm_core_kva(A, lda, B, ldb, K, m0, n0,
              As0, Bs0, As1, Bs1, As2, Bs2, As3, Bs3, acc);

  const int tid  = threadIdx.x;
  const int lane = tid & 63;
  const int w    = tid >> 6;
  const int wm   = w >> 1, wn = w & 1;
  const int l15  = lane & 15;
  const int quad = lane >> 4;

  if constexpr (MODE == 2) {
    f16* C = (f16*)Cout + (long)bz * cbatch;
#pragma unroll
    for (int i = 0; i < 4; ++i) {
      const int mg = m0 + wm * 64 + i * 16 + quad * 4;
#pragma unroll
      for (int j = 0; j < 4; ++j) {
        const int ng = n0 + wn * 64 + j * 16 + l15;
#pragma unroll
        for (int rr = 0; rr < 4; ++rr)
          C[(long)(mg + rr) * ldc + ng] = (f16)acc[i][j][rr];
      }
    }
  } else {  // MODE 3: attn, f32 out, scale by z
    float* C = (float*)Cout + (long)bz * cbatch;
#pragma unroll
    for (int i = 0; i < 4; ++i) {
      const int mg = m0 + wm * 64 + i * 16 + quad * 4;
      float zr[4];
#pragma unroll
      for (int rr = 0; rr < 4; ++rr) zr[rr] = zvec[(long)(mg + rr) * 4 + bz];
#pragma unroll
      for (int j = 0; j < 4; ++j) {
        const int ng = n0 + wn * 64 + j * 16 + l15;
#pragma unroll
        for (int rr = 0; rr < 4; ++rr)
          C[(long)(mg + rr) * ldc + ng] = acc[i][j][rr] * zr[rr];
      }
    }
  }
}

// ---------------------------------------------------------------------------
// fp16 64x64 LDS-tiled transpose, K and V fused in one launch.
// grid = (32, 32, 8): z<4 -> K batch z; z>=4 -> V batch z-4 (x<16 only).
__global__ void transpose_fused(const f16* __restrict__ Kn, f16* __restrict__ Kt,
                                const f16* __restrict__ Vp, f16* __restrict__ Vt) {
  __shared__ f16 tile[64 * 72];   // +8 halves pad (144B stride keeps 16B alignment)
  const int z = blockIdx.z;
  const f16* in;
  f16* out;
  long in_batch, out_batch;
  int ldin, ldout, b;
  if (z < 4) {
    in = Kn; out = Kt; in_batch = 2048; out_batch = 2048L * 2048;
    ldin = 8192; ldout = 2048; b = z;
  } else {
    if (blockIdx.x >= 16) return;   // V col dim is 1024 (uniform exit, pre-barrier)
    in = Vp; out = Vt; in_batch = 1024; out_batch = 1024L * 2048;
    ldin = 4096; ldout = 2048; b = z - 4;
  }
  in  += (long)b * in_batch;
  out += (long)b * out_batch;
  const int r0 = blockIdx.y * 64;
  const int c0 = blockIdx.x * 64;
  const int t  = threadIdx.x;
  {
    const int r = t >> 2, cs = (t & 3) * 16;
    const f16* src = in + (long)(r0 + r) * ldin + c0 + cs;
    f16x8 v0 = *(const f16x8*)(src);
    f16x8 v1 = *(const f16x8*)(src + 8);
    *(f16x8*)(tile + r * 72 + cs)     = v0;
    *(f16x8*)(tile + r * 72 + cs + 8) = v1;
  }
  __syncthreads();
  {
    const int c = t >> 2, rs = (t & 3) * 16;
    alignas(16) f16 tmp[16];
#pragma unroll
    for (int j = 0; j < 16; ++j) tmp[j] = tile[(rs + j) * 72 + c];
    f16* dst = out + (long)(c0 + c) * ldout + r0 + rs;
    *(f16x8*)(dst)     = *(const f16x8*)(tmp);
    *(f16x8*)(dst + 8) = *(const f16x8*)(tmp + 8);
  }
}

// ---------------------------------------------------------------------------
// k_sum[b][d] = sum_s K_t[b][d][s]  (one block per row of 2048)
__global__ void ksum_kernel(const f16* __restrict__ Kt, float* __restrict__ ks) {
  const long row = blockIdx.x;
  const int t = threadIdx.x;
  f16x8 v = *(const f16x8*)(Kt + row * 2048 + t * 8);
  float s = 0.f;
#pragma unroll
  for (int j = 0; j < 8; ++j) s += (float)v[j];
#pragma unroll
  for (int off = 32; off > 0; off >>= 1) s += __shfl_down(s, off, 64);
  __shared__ float red[4];
  if ((t & 63) == 0) red[t >> 6] = s;
  __syncthreads();
  if (t == 0) ks[row] = red[0] + red[1] + red[2] + red[3];
}

// z[r=l*4+b] = 1 / max(sum_d Q_[r][d] * k_sum[b][d], eps)
__global__ void z_kernel(const f16* __restrict__ Qf, const float* __restrict__ ks,
                         float* __restrict__ zb) {
  const long r = blockIdx.x;
  const int t = threadIdx.x;
  const int b = (int)(r & 3);
  f16x8 q = *(const f16x8*)(Qf + r * 2048 + t * 8);
  const float* kp = ks + b * 2048 + t * 8;
  float s = 0.f;
#pragma unroll
  for (int j = 0; j < 8; ++j) s += (float)q[j] * kp[j];
#pragma unroll
  for (int off = 32; off > 0; off >>= 1) s += __shfl_down(s, off, 64);
  __shared__ float red[4];
  if ((t & 63) == 0) red[t >> 6] = s;
  __syncthreads();
  if (t == 0) zb[r] = 1.f / fmaxf(red[0] + red[1] + red[2] + red[3], 1e-6f);
}

// ---------------------------------------------------------------------------
extern "C" void kernel_launch(void* const* d_in, const int* in_sizes, int n_in,
                              void* d_out, int out_size, void* d_ws, size_t ws_size,
                              hipStream_t stream) {
  const float* query = (const float*)d_in[0];
  const float* key_  = (const float*)d_in[1];
  const float* value = (const float*)d_in[2];
  const float* Wq    = (const float*)d_in[3];
  const float* bq    = (const float*)d_in[4];
  const float* Wk    = (const float*)d_in[5];
  const float* bk    = (const float*)d_in[6];
  const float* Wv    = (const float*)d_in[7];
  const float* bv    = (const float*)d_in[8];

  char* ws = (char*)d_ws;
  const size_t MB = 1ull << 20;
  // Workspace layout (peak 134 MB, with lifetime-based aliasing):
  f16* wq16 = (f16*)(ws + 0 * MB);    // 2 MB
  f16* wk16 = (f16*)(ws + 2 * MB);    // 2 MB
  f16* wv16 = (f16*)(ws + 4 * MB);    // 2 MB
  f16* q16  = (f16*)(ws + 6 * MB);    // 16 MB (dead after proj GEMMs)
  f16* k16  = (f16*)(ws + 22 * MB);   // 16 MB (dead after proj GEMMs)
  f16* v16  = (f16*)(ws + 38 * MB);   // 16 MB (dead after proj GEMMs)
  f16* Qf   = (f16*)(ws + 54 * MB);   // 32 MB  Q_ [l*4+b][2048]
  f16* Kn   = (f16*)(ws + 86 * MB);   // 32 MB  K_ natural [s*4+b][2048] (dead after transpose)
  f16* Vp   = (f16*)(ws + 118 * MB);  // 16 MB  V  natural [s*4+b][1024] (dead after transpose)
  f16* Kt   = (f16*)(ws + 6 * MB);    // 32 MB  K_t [b][d][s]   (aliases q16+k16)
  f16* Vt   = (f16*)(ws + 38 * MB);   // 16 MB  V_t [b][m][s]   (aliases v16)
  f16* kvb  = (f16*)(ws + 86 * MB);   // 16 MB  kv  [b][m][d]   (aliases Kn)
  float* ks = (float*)(ws + 102 * MB);  // 32 KB k_sum[b][d]
  float* zb = (float*)(ws + 103 * MB);  // 32 KB z[l*4+b]

  // 1) f32 -> f16 (2 fused launches)
  cvt3<<<dim3(8192, 1, 3), 256, 0, stream>>>(query, key_, value, q16, k16, v16, 2097152);
  cvt3<<<dim3(1024, 1, 3), 256, 0, stream>>>(Wq, Wk, Wv, wq16, wk16, wv16, 262144);

  // 2) projections fused (M=8192, N=1024, K=1024; z selects Q/K/V); 384 blocks
  proj_gemm<<<dim3(4, 32, 3), 512, 0, stream>>>(q16, k16, v16, wq16, wk16, wv16,
                                                bq, bk, bv, Qf, Kn, Vp);

  // 3) transposes fused: K_ [s][d] -> K_t [d][s]; V [s][m] -> V_t [m][s]
  transpose_fused<<<dim3(32, 32, 8), 256, 0, stream>>>(Kn, Kt, Vp, Vt);

  // 4) k_sum and z
  ksum_kernel<<<8192, 256, 0, stream>>>(Kt, ks);
  z_kernel<<<8192, 256, 0, stream>>>(Qf, ks, zb);

  // 5) kv[b][m][d] = sum_s V_t[m][s] * K_t[d][s]  (M=1024, N=2048, K=2048); 256 blocks
  gemm_bt<2><<<dim3(16, 4, 4), 512, 0, stream>>>(Vt, 2048, Kt, 2048, kvb, 2048, 2048,
                                                 nullptr, 1024L * 2048, 2048L * 2048, 1024L * 2048);
  // 6) attn[l][b][m] = z * sum_d Q_[l][d] * kv[m][d]  (M=2048, N=1024, K=2048); 256 blocks
  gemm_bt<3><<<dim3(8, 8, 4), 512, 0, stream>>>(Qf, 8192, kvb, 2048, d_out, 2048, 4096,
                                                zb, 2048, 1024L * 2048, 1024);
}

// Round 15
// 377.428 us; speedup vs baseline: 1.0962x; 1.0046x over previous
//
#include <hip/hip_runtime.h>
#include <hip/hip_fp16.h>

// cosFormer linear attention, MI355X. L=S=2048, B=4, E=1024.
// R1: fused launches. R2: XCD swizzle (FETCH 204->49MB = ideal). R3: runtime
// dbuf regressed (alias-conservative vmcnt0). R5: static dbuf neutral.
// R7: counted-vmcnt depth-2 256x128 (kv/attn keep this). R8: regressed.
// R9/R12: fine-phase 256sq proj = 100.4us, MfmaUtil ~20% (neutral; five
//     schedule families all pin at ~2 TF/CU on these shapes).
// R13: ksum-in-transpose fold -> NaN FAIL. ROOT CAUSE: ks@ws+102MB aliases
//     Kn rows 1024-1025 ([86,118)). Early zero was clobbered by proj's Kn
//     writes, and transpose's ksum atomics raced with transpose reads of
//     those same Kn bytes -> arbitrary bit patterns (incl. f16 NaN) in Kt.
//     Lesson: every byte under 134MB is written between cvt and transpose,
//     so an early-zeroed accumulator has no safe home in this layout.
// R15: revert fold; restore R12-proven ksum_kernel (overwrite, no zero,
//     runs after Kn dead). Keep only the alias-free cvt fusion:
//     cvt_all grid (9216,1,3), pure conversion. 7 dispatches.

typedef _Float16 f16;
typedef f16 f16x8 __attribute__((ext_vector_type(8)));
typedef f16 f16x4 __attribute__((ext_vector_type(4)));
typedef float f32x4 __attribute__((ext_vector_type(4)));

#define AS1 __attribute__((address_space(1)))
#define AS3 __attribute__((address_space(3)))

__device__ __forceinline__ void gload_lds16(const void* g, void* l) {
  // async global->LDS, 16B/lane; LDS dest = wave-uniform base + lane*16
  __builtin_amdgcn_global_load_lds((const AS1 void*)g, (AS3 void*)l, 16, 0, 0);
}

// XCD-chunked bijective swizzle (T1). Requires nwg % 8 == 0 (all our grids).
__device__ __forceinline__ void xcd_swz(int& bx, int& by, int& bz) {
  const int nx = gridDim.x, ny = gridDim.y;
  const int p = blockIdx.x + nx * (blockIdx.y + ny * blockIdx.z);
  const int chunk = (nx * ny * gridDim.z) >> 3;
  const int l = (p & 7) * chunk + (p >> 3);
  bx = l % nx;
  by = (l / nx) % ny;
  bz = l / (nx * ny);
}

// ---------------------------------------------------------------------------
// Fused f32->f16 convert for all 6 tensors. grid (9216, 1, 3).
// x <  8192 : big arrays (q/k/v), idx = x*256+t  (8192*256 = 2097152 exact)
// x >= 8192 : weights (Wq/Wk/Wv), idx = (x-8192)*256+t (262144 exact)
__global__ void cvt_all(const float* __restrict__ q, const float* __restrict__ k,
                        const float* __restrict__ v, const float* __restrict__ Wq,
                        const float* __restrict__ Wk, const float* __restrict__ Wv,
                        f16* __restrict__ q16, f16* __restrict__ k16,
                        f16* __restrict__ v16, f16* __restrict__ wq16,
                        f16* __restrict__ wk16, f16* __restrict__ wv16) {
  const int z = blockIdx.z;
  const int x = blockIdx.x;
  const float* s;
  f16* d;
  int i;
  if (x < 8192) {
    s = (z == 0) ? q : (z == 1) ? k : v;
    d = (z == 0) ? q16 : (z == 1) ? k16 : v16;
    i = x * 256 + threadIdx.x;
  } else {
    s = (z == 0) ? Wq : (z == 1) ? Wk : Wv;
    d = (z == 0) ? wq16 : (z == 1) ? wk16 : wv16;
    i = (x - 8192) * 256 + threadIdx.x;
  }
  const float4 vv = ((const float4*)s)[i];
  f16x4 o = { (f16)vv.x, (f16)vv.y, (f16)vv.z, (f16)vv.w };
  ((f16x4*)d)[i] = o;
}

// ---------------------------------------------------------------------------
// Fused Q/K/V projection GEMM, fine-phase 256x256 core (R9, measured 100.4us).
// grid=(4,32,3), 512thr. z=0: Q->Qf (relu+bias, sin/cos dual, ldc=2048);
// z=1: K->Kn (same); z=2: V->Vp (bias only, ldc=1024).
// LDS per buffer: A-tile 256x64 as 32 fragment-blocks of 1KB (bid=mt*2+kt;
// lane l: row mt*16+(l&15), k kt*32+(l>>4)*8..+7); B-tile same by ntile.
// Wave w (wm=w>>2, wn=w&3): 4 scattered 64x32 quadrants; phase (qm,qn)
// touches exactly halves (Ah_qm, Bh_qn); stage order Ah0,Bh0,Bh1,Ah1.
__launch_bounds__(512, 2)
__global__ void proj_gemm(const f16* __restrict__ q16, const f16* __restrict__ k16,
                          const f16* __restrict__ v16, const f16* __restrict__ wq,
                          const f16* __restrict__ wk, const f16* __restrict__ wv,
                          const float* __restrict__ bq, const float* __restrict__ bk,
                          const float* __restrict__ bv,
                          f16* __restrict__ Qf, f16* __restrict__ Kn, f16* __restrict__ Vp) {
  __shared__ alignas(16) f16 As0[16384];   // 32 KB
  __shared__ alignas(16) f16 Bs0[16384];
  __shared__ alignas(16) f16 As1[16384];
  __shared__ alignas(16) f16 Bs1[16384];

  int bx, by, z;
  xcd_swz(bx, by, z);
  const f16* A = (z == 0) ? q16 : (z == 1) ? k16 : v16;
  const f16* B = (z == 0) ? wq : (z == 1) ? wk : wv;
  const float* bias = (z == 0) ? bq : (z == 1) ? bk : bv;
  const int m0 = by * 256;
  const int n0 = bx * 256;

  const int tid  = threadIdx.x;
  const int lane = tid & 63;
  const int w    = tid >> 6;        // 0..7
  const int wm   = w >> 2;          // 0..1
  const int wn   = w & 3;           // 0..3
  const int l15  = lane & 15;
  const int quad = lane >> 4;
  const int lda = 1024, ldb = 1024, K = 1024;

  const f16* gA0 = A + (long)(m0 + w * 16 + l15) * lda + quad * 8;
  const f16* gA1 = gA0 + 128 * lda;
  const f16* gB0 = B + (long)(n0 + w * 16 + l15) * ldb + quad * 8;
  const f16* gB1 = gB0 + 128 * ldb;
  int ko = 0;

  f32x4 acc[4][4][2] = {};          // [quadrant][mi][nj], literal-indexed
  f16x8 af[4][2], bf[2][2];

#define ST_AH0(AW) do { gload_lds16(gA0 + ko, (AW) + w * 1024); \
                        gload_lds16(gA0 + ko + 32, (AW) + w * 1024 + 512); } while (0)
#define ST_AH1(AW) do { gload_lds16(gA1 + ko, (AW) + (8 + w) * 1024); \
                        gload_lds16(gA1 + ko + 32, (AW) + (8 + w) * 1024 + 512); } while (0)
#define ST_BH0(BW) do { gload_lds16(gB0 + ko, (BW) + w * 1024); \
                        gload_lds16(gB0 + ko + 32, (BW) + w * 1024 + 512); } while (0)
#define ST_BH1(BW) do { gload_lds16(gB1 + ko, (BW) + (8 + w) * 1024); \
                        gload_lds16(gB1 + ko + 32, (BW) + (8 + w) * 1024 + 512); } while (0)

#define RD_AF(AR, qm) do { _Pragma("unroll") \
    for (int mi = 0; mi < 4; ++mi) { _Pragma("unroll") \
      for (int kt = 0; kt < 2; ++kt) \
        af[mi][kt] = *(const f16x8*)((AR) + (((qm) * 8 + wm * 4 + mi) * 2 + kt) * 512 + lane * 8); } } while (0)
#define RD_BF(BR, qn) do { _Pragma("unroll") \
    for (int nj = 0; nj < 2; ++nj) { _Pragma("unroll") \
      for (int kt = 0; kt < 2; ++kt) \
        bf[nj][kt] = *(const f16x8*)((BR) + (((qn) * 8 + wn * 2 + nj) * 2 + kt) * 512 + lane * 8); } } while (0)

#define MF16(q) do { __builtin_amdgcn_s_setprio(1); _Pragma("unroll") \
    for (int mi = 0; mi < 4; ++mi) { _Pragma("unroll") \
      for (int nj = 0; nj < 2; ++nj) { _Pragma("unroll") \
        for (int kt = 0; kt < 2; ++kt) \
          acc[q][mi][nj] = __builtin_amdgcn_mfma_f32_16x16x32_f16(af[mi][kt], bf[nj][kt], acc[q][mi][nj], 0, 0, 0); } } \
    __builtin_amdgcn_s_setprio(0); } while (0)

#define WV4_ asm volatile("s_waitcnt vmcnt(4)" ::: "memory")
#define WV2_ asm volatile("s_waitcnt vmcnt(2)" ::: "memory")
#define WV0_ asm volatile("s_waitcnt vmcnt(0)" ::: "memory")
#define BARR_ do { __builtin_amdgcn_s_barrier(); __builtin_amdgcn_sched_barrier(0); } while (0)

#define TILE(AR, BR, AW, BW) do {                                  \
    WV4_; BARR_; ST_AH0(AW); RD_AF(AR, 0); RD_BF(BR, 0); MF16(0);  \
    WV4_; BARR_; ST_BH0(BW); RD_BF(BR, 1); MF16(1);                \
    WV4_; BARR_; ST_BH1(BW); RD_AF(AR, 1); MF16(2);                \
          BARR_; ST_AH1(AW); RD_BF(BR, 0); MF16(3);                \
    ko += 64; } while (0)

#define TILE_LAST(AR, BR) do {                                     \
    WV4_; BARR_; RD_AF(AR, 0); RD_BF(BR, 0); MF16(0);              \
    WV2_; BARR_; RD_BF(BR, 1); MF16(1);                            \
    WV0_; BARR_; RD_AF(AR, 1); MF16(2);                            \
          BARR_; RD_BF(BR, 0); MF16(3); } while (0)

  // prologue: stage tile 0 fully (same half order), then uniform loop
  ST_AH0(As0); ST_BH0(Bs0); ST_BH1(Bs0); ST_AH1(As0);
  ko = 64;

  const int nt = K >> 6;            // 16
  for (int t = 0; t + 2 < nt; t += 2) {
    TILE(As0, Bs0, As1, Bs1);
    TILE(As1, Bs1, As0, Bs0);
  }
  TILE(As0, Bs0, As1, Bs1);         // tile nt-2 (stages tile nt-1)
  TILE_LAST(As1, Bs1);              // tile nt-1

#undef ST_AH0
#undef ST_AH1
#undef ST_BH0
#undef ST_BH1
#undef RD_AF
#undef RD_BF
#undef MF16
#undef WV4_
#undef WV2_
#undef WV0_
#undef BARR_
#undef TILE
#undef TILE_LAST

  // Epilogue. C/D layout (verified m89/m91): col = lane&15, row = quad*4 + reg.
  const int QM[4] = {0, 0, 1, 1};
  const int QN[4] = {0, 1, 1, 0};
  if (z < 2) {
    f16* C = (z == 0) ? Qf : Kn;
    const int ldc = 2048, halfw = 1024;
#pragma unroll
    for (int q = 0; q < 4; ++q) {
      const int rbase = m0 + QM[q] * 128 + wm * 64;
      const int cbase = n0 + QN[q] * 128 + wn * 32;
#pragma unroll
      for (int mi = 0; mi < 4; ++mi) {
        const int mg = rbase + mi * 16 + quad * 4;
        float sn[4], cn[4];
#pragma unroll
        for (int rr = 0; rr < 4; ++rr) {
          const int l = (mg + rr) >> 2;          // natural row = l*4 + b
          const float ang = 7.6699039394282066e-4f * (float)(l + 1);  // (pi/2)/2048*(l+1)
          __sincosf(ang, &sn[rr], &cn[rr]);
        }
#pragma unroll
        for (int nj = 0; nj < 2; ++nj) {
          const int ng = cbase + nj * 16 + l15;
          const float bc = bias[ng];
#pragma unroll
          for (int rr = 0; rr < 4; ++rr) {
            const float v = fmaxf(acc[q][mi][nj][rr] + bc, 0.f);
            C[(long)(mg + rr) * ldc + ng]         = (f16)(v * sn[rr]);
            C[(long)(mg + rr) * ldc + ng + halfw] = (f16)(v * cn[rr]);
          }
        }
      }
    }
  } else {
    f16* C = Vp;
    const int ldc = 1024;
#pragma unroll
    for (int q = 0; q < 4; ++q) {
      const int rbase = m0 + QM[q] * 128 + wm * 64;
      const int cbase = n0 + QN[q] * 128 + wn * 32;
#pragma unroll
      for (int mi = 0; mi < 4; ++mi) {
        const int mg = rbase + mi * 16 + quad * 4;
#pragma unroll
        for (int nj = 0; nj < 2; ++nj) {
          const int ng = cbase + nj * 16 + l15;
          const float bc = bias[ng];
#pragma unroll
          for (int rr = 0; rr < 4; ++rr)
            C[(long)(mg + rr) * ldc + ng] = (f16)(acc[q][mi][nj][rr] + bc);
        }
      }
    }
  }
}

// ---------------------------------------------------------------------------
// R7 core (verbatim): depth-2 counted-vmcnt 256x128xBK32, 8 waves, 96KB LDS.
// Used for kv and attn stages (their best measured config).
__device__ __forceinline__ void mm_core_kva(const f16* __restrict__ A, int lda,
                                            const f16* __restrict__ B, int ldb,
                                            int K, int m0, int n0,
                                            f16* As0, f16* Bs0, f16* As1, f16* Bs1,
                                            f16* As2, f16* Bs2, f16* As3, f16* Bs3,
                                            f32x4 (&acc)[4][4]) {
  const int tid  = threadIdx.x;
  const int lane = tid & 63;
  const int w    = tid >> 6;        // wave 0..7
  const int wm   = w >> 1, wn = w & 1;
  const int l15  = lane & 15;
  const int quad = lane >> 4;

  const f16* pa0 = A + (long)(m0 + w * 16 + l15) * lda + quad * 8;        // A block w
  const f16* pa1 = A + (long)(m0 + (8 + w) * 16 + l15) * lda + quad * 8;  // A block 8+w
  const f16* pb0 = B + (long)(n0 + w * 16 + l15) * ldb + quad * 8;        // B block w
  int koff = 0;

#define STAGE_(Ab, Bb) do {                        \
    gload_lds16(pa0 + koff, (Ab) + w * 512);       \
    gload_lds16(pa1 + koff, (Ab) + (8 + w) * 512); \
    gload_lds16(pb0 + koff, (Bb) + w * 512);       \
    koff += 32; } while (0)

#define COMPUTE_(Ab, Bb) do {                                                    \
    f16x8 af[4], bf[4];                                                          \
    _Pragma("unroll")                                                            \
    for (int i = 0; i < 4; ++i)                                                  \
      af[i] = *(const f16x8*)((Ab) + (wm * 4 + i) * 512 + lane * 8);             \
    _Pragma("unroll")                                                            \
    for (int j = 0; j < 4; ++j)                                                  \
      bf[j] = *(const f16x8*)((Bb) + (wn * 4 + j) * 512 + lane * 8);             \
    _Pragma("unroll")                                                            \
    for (int i = 0; i < 4; ++i)                                                  \
      _Pragma("unroll")                                                          \
      for (int j = 0; j < 4; ++j)                                                \
        acc[i][j] = __builtin_amdgcn_mfma_f32_16x16x32_f16(af[i], bf[j],         \
                                                           acc[i][j], 0, 0, 0); \
  } while (0)

#define WV3_ asm volatile("s_waitcnt vmcnt(3)" ::: "memory")
#define WV0_ asm volatile("s_waitcnt vmcnt(0)" ::: "memory")
#define BARR_ do { __builtin_amdgcn_s_barrier(); __builtin_amdgcn_sched_barrier(0); } while (0)

  // prologue: 2 stages in flight
  STAGE_(As0, Bs0);
  STAGE_(As1, Bs1);

  const int nt = K >> 5;            // 64 for K=2048; nt % 4 == 0
  for (int t = 0; t + 5 < nt; t += 4) {
    WV3_; BARR_; STAGE_(As2, Bs2); COMPUTE_(As0, Bs0);
    WV3_; BARR_; STAGE_(As3, Bs3); COMPUTE_(As1, Bs1);
    WV3_; BARR_; STAGE_(As0, Bs0); COMPUTE_(As2, Bs2);
    WV3_; BARR_; STAGE_(As1, Bs1); COMPUTE_(As3, Bs3);
  }
  // peeled final 4 sub-steps
  WV3_; BARR_; STAGE_(As2, Bs2); COMPUTE_(As0, Bs0);
  WV3_; BARR_; STAGE_(As3, Bs3); COMPUTE_(As1, Bs1);
  WV3_; BARR_; COMPUTE_(As2, Bs2);
  WV0_; BARR_; COMPUTE_(As3, Bs3);

#undef STAGE_
#undef COMPUTE_
#undef WV3_
#undef WV0_
#undef BARR_
}

#define GEMM_LDS                                   \
  __shared__ alignas(16) f16 As0[8192];            \
  __shared__ alignas(16) f16 Bs0[4096];            \
  __shared__ alignas(16) f16 As1[8192];            \
  __shared__ alignas(16) f16 Bs1[4096];            \
  __shared__ alignas(16) f16 As2[8192];            \
  __shared__ alignas(16) f16 Bs2[4096];            \
  __shared__ alignas(16) f16 As3[8192];            \
  __shared__ alignas(16) f16 Bs3[4096];

// ---------------------------------------------------------------------------
// Generic GEMM (kv and attn stages), 512 thr, BM=256/BN=128 (R7 verbatim).
// MODE 2: kv   -> f16 C = acc
// MODE 3: attn -> f32 C = acc * z[l*4+bz]
template<int MODE>
__launch_bounds__(512, 2)
__global__ void gemm_bt(const f16* __restrict__ A, int lda,
                        const f16* __restrict__ B, int ldb,
                        void* __restrict__ Cout, int K, int ldc,
                        const float* __restrict__ zvec,
                        long abatch, long bbatch, long cbatch)
{
  GEMM_LDS
  int bx, by, bz;
  xcd_swz(bx, by, bz);
  A += (long)bz * abatch;
  B += (long)bz * bbatch;
  const int m0 = by * 256;
  const int n0 = bx * 128;

  f32x4 acc[4][4] = {};
  mm_core_kva(A, lda, B, ldb, K, m0, n0,
              As0, Bs0, As1, Bs1, As2, Bs2, As3, Bs3, acc);

  const int tid  = threadIdx.x;
  const int lane = tid & 63;
  const int w    = tid >> 6;
  const int wm   = w >> 1, wn = w & 1;
  const int l15  = lane & 15;
  const int quad = lane >> 4;

  if constexpr (MODE == 2) {
    f16* C = (f16*)Cout + (long)bz * cbatch;
#pragma unroll
    for (int i = 0; i < 4; ++i) {
      const int mg = m0 + wm * 64 + i * 16 + quad * 4;
#pragma unroll
      for (int j = 0; j < 4; ++j) {
        const int ng = n0 + wn * 64 + j * 16 + l15;
#pragma unroll
        for (int rr = 0; rr < 4; ++rr)
          C[(long)(mg + rr) * ldc + ng] = (f16)acc[i][j][rr];
      }
    }
  } else {  // MODE 3: attn, f32 out, scale by z
    float* C = (float*)Cout + (long)bz * cbatch;
#pragma unroll
    for (int i = 0; i < 4; ++i) {
      const int mg = m0 + wm * 64 + i * 16 + quad * 4;
      float zr[4];
#pragma unroll
      for (int rr = 0; rr < 4; ++rr) zr[rr] = zvec[(long)(mg + rr) * 4 + bz];
#pragma unroll
      for (int j = 0; j < 4; ++j) {
        const int ng = n0 + wn * 64 + j * 16 + l15;
#pragma unroll
        for (int rr = 0; rr < 4; ++rr)
          C[(long)(mg + rr) * ldc + ng] = acc[i][j][rr] * zr[rr];
      }
    }
  }
}

// ---------------------------------------------------------------------------
// fp16 64x64 LDS-tiled transpose, K and V fused in one launch (R12 verbatim).
// grid = (32, 32, 8): z<4 -> K batch z; z>=4 -> V batch z-4 (x<16 only).
__global__ void transpose_fused(const f16* __restrict__ Kn, f16* __restrict__ Kt,
                                const f16* __restrict__ Vp, f16* __restrict__ Vt) {
  __shared__ f16 tile[64 * 72];   // +8 halves pad (144B stride keeps 16B alignment)
  const int z = blockIdx.z;
  const f16* in;
  f16* out;
  long in_batch, out_batch;
  int ldin, ldout, b;
  if (z < 4) {
    in = Kn; out = Kt; in_batch = 2048; out_batch = 2048L * 2048;
    ldin = 8192; ldout = 2048; b = z;
  } else {
    if (blockIdx.x >= 16) return;   // V col dim is 1024 (uniform exit, pre-barrier)
    in = Vp; out = Vt; in_batch = 1024; out_batch = 1024L * 2048;
    ldin = 4096; ldout = 2048; b = z - 4;
  }
  in  += (long)b * in_batch;
  out += (long)b * out_batch;
  const int r0 = blockIdx.y * 64;
  const int c0 = blockIdx.x * 64;
  const int t  = threadIdx.x;
  {
    const int r = t >> 2, cs = (t & 3) * 16;
    const f16* src = in + (long)(r0 + r) * ldin + c0 + cs;
    f16x8 v0 = *(const f16x8*)(src);
    f16x8 v1 = *(const f16x8*)(src + 8);
    *(f16x8*)(tile + r * 72 + cs)     = v0;
    *(f16x8*)(tile + r * 72 + cs + 8) = v1;
  }
  __syncthreads();
  {
    const int c = t >> 2, rs = (t & 3) * 16;
    alignas(16) f16 tmp[16];
#pragma unroll
    for (int j = 0; j < 16; ++j) tmp[j] = tile[(rs + j) * 72 + c];
    f16* dst = out + (long)(c0 + c) * ldout + r0 + rs;
    *(f16x8*)(dst)     = *(const f16x8*)(tmp);
    *(f16x8*)(dst + 8) = *(const f16x8*)(tmp + 8);
  }
}

// ---------------------------------------------------------------------------
// k_sum[b][d] = sum_s K_t[b][d][s]  (one block per row of 2048; overwrite,
// no zeroing needed; runs after Kn is dead so ks@102MB aliasing is safe)
__global__ void ksum_kernel(const f16* __restrict__ Kt, float* __restrict__ ks) {
  const long row = blockIdx.x;
  const int t = threadIdx.x;
  f16x8 v = *(const f16x8*)(Kt + row * 2048 + t * 8);
  float s = 0.f;
#pragma unroll
  for (int j = 0; j < 8; ++j) s += (float)v[j];
#pragma unroll
  for (int off = 32; off > 0; off >>= 1) s += __shfl_down(s, off, 64);
  __shared__ float red[4];
  if ((t & 63) == 0) red[t >> 6] = s;
  __syncthreads();
  if (t == 0) ks[row] = red[0] + red[1] + red[2] + red[3];
}

// z[r=l*4+b] = 1 / max(sum_d Q_[r][d] * k_sum[b][d], eps)
__global__ void z_kernel(const f16* __restrict__ Qf, const float* __restrict__ ks,
                         float* __restrict__ zb) {
  const long r = blockIdx.x;
  const int t = threadIdx.x;
  const int b = (int)(r & 3);
  f16x8 q = *(const f16x8*)(Qf + r * 2048 + t * 8);
  const float* kp = ks + b * 2048 + t * 8;
  float s = 0.f;
#pragma unroll
  for (int j = 0; j < 8; ++j) s += (float)q[j] * kp[j];
#pragma unroll
  for (int off = 32; off > 0; off >>= 1) s += __shfl_down(s, off, 64);
  __shared__ float red[4];
  if ((t & 63) == 0) red[t >> 6] = s;
  __syncthreads();
  if (t == 0) zb[r] = 1.f / fmaxf(red[0] + red[1] + red[2] + red[3], 1e-6f);
}

// ---------------------------------------------------------------------------
extern "C" void kernel_launch(void* const* d_in, const int* in_sizes, int n_in,
                              void* d_out, int out_size, void* d_ws, size_t ws_size,
                              hipStream_t stream) {
  const float* query = (const float*)d_in[0];
  const float* key_  = (const float*)d_in[1];
  const float* value = (const float*)d_in[2];
  const float* Wq    = (const float*)d_in[3];
  const float* bq    = (const float*)d_in[4];
  const float* Wk    = (const float*)d_in[5];
  const float* bk    = (const float*)d_in[6];
  const float* Wv    = (const float*)d_in[7];
  const float* bv    = (const float*)d_in[8];

  char* ws = (char*)d_ws;
  const size_t MB = 1ull << 20;
  // Workspace layout (peak 134 MB, lifetime-based aliasing). NOTE: ks/zb at
  // [102,104) alias Kn rows 1024-1025 -> they may only be written AFTER the
  // transpose (Kn's last reader) completes. (R13's early-zero broke this.)
  f16* wq16 = (f16*)(ws + 0 * MB);    // 2 MB
  f16* wk16 = (f16*)(ws + 2 * MB);    // 2 MB
  f16* wv16 = (f16*)(ws + 4 * MB);    // 2 MB
  f16* q16  = (f16*)(ws + 6 * MB);    // 16 MB (dead after proj GEMMs)
  f16* k16  = (f16*)(ws + 22 * MB);   // 16 MB (dead after proj GEMMs)
  f16* v16  = (f16*)(ws + 38 * MB);   // 16 MB (dead after proj GEMMs)
  f16* Qf   = (f16*)(ws + 54 * MB);   // 32 MB  Q_ [l*4+b][2048]
  f16* Kn   = (f16*)(ws + 86 * MB);   // 32 MB  K_ natural [s*4+b][2048] (dead after transpose)
  f16* Vp   = (f16*)(ws + 118 * MB);  // 16 MB  V  natural [s*4+b][1024] (dead after transpose)
  f16* Kt   = (f16*)(ws + 6 * MB);    // 32 MB  K_t [b][d][s]   (aliases q16+k16)
  f16* Vt   = (f16*)(ws + 38 * MB);   // 16 MB  V_t [b][m][s]   (aliases v16)
  f16* kvb  = (f16*)(ws + 86 * MB);   // 16 MB  kv  [b][m][d]   (aliases Kn)
  float* ks = (float*)(ws + 102 * MB);  // 32 KB k_sum[b][d]  (write AFTER transpose only)
  float* zb = (float*)(ws + 103 * MB);  // 32 KB z[l*4+b]     (write AFTER transpose only)

  // 1) f32 -> f16 for all 6 tensors (one launch)
  cvt_all<<<dim3(9216, 1, 3), 256, 0, stream>>>(query, key_, value, Wq, Wk, Wv,
                                                q16, k16, v16, wq16, wk16, wv16);

  // 2) projections fused (M=8192, N=1024, K=1024; z selects Q/K/V); 384 blocks
  proj_gemm<<<dim3(4, 32, 3), 512, 0, stream>>>(q16, k16, v16, wq16, wk16, wv16,
                                                bq, bk, bv, Qf, Kn, Vp);

  // 3) transposes fused: K_ [s][d] -> K_t [d][s]; V [s][m] -> V_t [m][s]
  transpose_fused<<<dim3(32, 32, 8), 256, 0, stream>>>(Kn, Kt, Vp, Vt);

  // 4) k_sum and z (after transpose: Kn dead, ks/zb aliasing safe)
  ksum_kernel<<<8192, 256, 0, stream>>>(Kt, ks);
  z_kernel<<<8192, 256, 0, stream>>>(Qf, ks, zb);

  // 5) kv[b][m][d] = sum_s V_t[m][s] * K_t[d][s]  (M=1024, N=2048, K=2048); 256 blocks
  gemm_bt<2><<<dim3(16, 4, 4), 512, 0, stream>>>(Vt, 2048, Kt, 2048, kvb, 2048, 2048,
                                                 nullptr, 1024L * 2048, 2048L * 2048, 1024L * 2048);
  // 6) attn[l][b][m] = z * sum_d Q_[l][d] * kv[m][d]  (M=2048, N=1024, K=2048); 256 blocks
  gemm_bt<3><<<dim3(8, 8, 4), 512, 0, stream>>>(Qf, 8192, kvb, 2048, d_out, 2048, 4096,
                                                zb, 2048, 1024L * 2048, 1024);
}

// Round 17
// 373.564 us; speedup vs baseline: 1.1075x; 1.0103x over previous
//
#include <hip/hip_runtime.h>
#include <hip/hip_fp16.h>

// cosFormer linear attention, MI355X. L=S=2048, B=4, E=1024.
// R1: fused launches. R2: XCD swizzle (FETCH ideal). R3/R5/R7/R8/R9: five
//     GEMM schedule families all pin at ~2 TF/CU (MfmaUtil 15-20%) on these
//     small-N shapes (consistent with m102's shape curve); proj=R9 fine-phase
//     (100-104us), kv/attn=R7 depth-2 counted-vmcnt (best measured).
// R13: ksum-in-transpose fold -> NaN: ks@ws+102MB aliased Kn rows 1024-1025;
//     atomics raced transpose reads of the same bytes. Fold logic was sound.
// R15: revert fold, keep alias-free cvt fusion. 377.4us (plateau).
// R16: ws_size-GATED ksum fold: if ws_size >= 135MB, relocate ks to ws+134MB
//     (beyond all lifetimes -> alias-free), hipMemsetAsync-zero it, fold ksum
//     into transpose K-blocks (4-lane shfl reduce -> 64 atomicAdd/block,
//     32 adds/address), skip ksum_kernel (7 -> 6 dispatches). Small-ws
//     fallback = exact R15 path. One reversible change.
// R17: resubmission of R16 (round 16 hit GPU-acquisition timeout).

typedef _Float16 f16;
typedef f16 f16x8 __attribute__((ext_vector_type(8)));
typedef f16 f16x4 __attribute__((ext_vector_type(4)));
typedef float f32x4 __attribute__((ext_vector_type(4)));

#define AS1 __attribute__((address_space(1)))
#define AS3 __attribute__((address_space(3)))

__device__ __forceinline__ void gload_lds16(const void* g, void* l) {
  // async global->LDS, 16B/lane; LDS dest = wave-uniform base + lane*16
  __builtin_amdgcn_global_load_lds((const AS1 void*)g, (AS3 void*)l, 16, 0, 0);
}

// XCD-chunked bijective swizzle (T1). Requires nwg % 8 == 0 (all our grids).
__device__ __forceinline__ void xcd_swz(int& bx, int& by, int& bz) {
  const int nx = gridDim.x, ny = gridDim.y;
  const int p = blockIdx.x + nx * (blockIdx.y + ny * blockIdx.z);
  const int chunk = (nx * ny * gridDim.z) >> 3;
  const int l = (p & 7) * chunk + (p >> 3);
  bx = l % nx;
  by = (l / nx) % ny;
  bz = l / (nx * ny);
}

// ---------------------------------------------------------------------------
// Fused f32->f16 convert for all 6 tensors. grid (9216, 1, 3).
// x <  8192 : big arrays (q/k/v), idx = x*256+t  (8192*256 = 2097152 exact)
// x >= 8192 : weights (Wq/Wk/Wv), idx = (x-8192)*256+t (262144 exact)
__global__ void cvt_all(const float* __restrict__ q, const float* __restrict__ k,
                        const float* __restrict__ v, const float* __restrict__ Wq,
                        const float* __restrict__ Wk, const float* __restrict__ Wv,
                        f16* __restrict__ q16, f16* __restrict__ k16,
                        f16* __restrict__ v16, f16* __restrict__ wq16,
                        f16* __restrict__ wk16, f16* __restrict__ wv16) {
  const int z = blockIdx.z;
  const int x = blockIdx.x;
  const float* s;
  f16* d;
  int i;
  if (x < 8192) {
    s = (z == 0) ? q : (z == 1) ? k : v;
    d = (z == 0) ? q16 : (z == 1) ? k16 : v16;
    i = x * 256 + threadIdx.x;
  } else {
    s = (z == 0) ? Wq : (z == 1) ? Wk : Wv;
    d = (z == 0) ? wq16 : (z == 1) ? wk16 : wv16;
    i = (x - 8192) * 256 + threadIdx.x;
  }
  const float4 vv = ((const float4*)s)[i];
  f16x4 o = { (f16)vv.x, (f16)vv.y, (f16)vv.z, (f16)vv.w };
  ((f16x4*)d)[i] = o;
}

// ---------------------------------------------------------------------------
// Fused Q/K/V projection GEMM, fine-phase 256x256 core (R9, measured ~102us).
// grid=(4,32,3), 512thr. z=0: Q->Qf (relu+bias, sin/cos dual, ldc=2048);
// z=1: K->Kn (same); z=2: V->Vp (bias only, ldc=1024).
// LDS per buffer: A-tile 256x64 as 32 fragment-blocks of 1KB (bid=mt*2+kt;
// lane l: row mt*16+(l&15), k kt*32+(l>>4)*8..+7); B-tile same by ntile.
// Wave w (wm=w>>2, wn=w&3): 4 scattered 64x32 quadrants; phase (qm,qn)
// touches exactly halves (Ah_qm, Bh_qn); stage order Ah0,Bh0,Bh1,Ah1.
__launch_bounds__(512, 2)
__global__ void proj_gemm(const f16* __restrict__ q16, const f16* __restrict__ k16,
                          const f16* __restrict__ v16, const f16* __restrict__ wq,
                          const f16* __restrict__ wk, const f16* __restrict__ wv,
                          const float* __restrict__ bq, const float* __restrict__ bk,
                          const float* __restrict__ bv,
                          f16* __restrict__ Qf, f16* __restrict__ Kn, f16* __restrict__ Vp) {
  __shared__ alignas(16) f16 As0[16384];   // 32 KB
  __shared__ alignas(16) f16 Bs0[16384];
  __shared__ alignas(16) f16 As1[16384];
  __shared__ alignas(16) f16 Bs1[16384];

  int bx, by, z;
  xcd_swz(bx, by, z);
  const f16* A = (z == 0) ? q16 : (z == 1) ? k16 : v16;
  const f16* B = (z == 0) ? wq : (z == 1) ? wk : wv;
  const float* bias = (z == 0) ? bq : (z == 1) ? bk : bv;
  const int m0 = by * 256;
  const int n0 = bx * 256;

  const int tid  = threadIdx.x;
  const int lane = tid & 63;
  const int w    = tid >> 6;        // 0..7
  const int wm   = w >> 2;          // 0..1
  const int wn   = w & 3;           // 0..3
  const int l15  = lane & 15;
  const int quad = lane >> 4;
  const int lda = 1024, ldb = 1024, K = 1024;

  const f16* gA0 = A + (long)(m0 + w * 16 + l15) * lda + quad * 8;
  const f16* gA1 = gA0 + 128 * lda;
  const f16* gB0 = B + (long)(n0 + w * 16 + l15) * ldb + quad * 8;
  const f16* gB1 = gB0 + 128 * ldb;
  int ko = 0;

  f32x4 acc[4][4][2] = {};          // [quadrant][mi][nj], literal-indexed
  f16x8 af[4][2], bf[2][2];

#define ST_AH0(AW) do { gload_lds16(gA0 + ko, (AW) + w * 1024); \
                        gload_lds16(gA0 + ko + 32, (AW) + w * 1024 + 512); } while (0)
#define ST_AH1(AW) do { gload_lds16(gA1 + ko, (AW) + (8 + w) * 1024); \
                        gload_lds16(gA1 + ko + 32, (AW) + (8 + w) * 1024 + 512); } while (0)
#define ST_BH0(BW) do { gload_lds16(gB0 + ko, (BW) + w * 1024); \
                        gload_lds16(gB0 + ko + 32, (BW) + w * 1024 + 512); } while (0)
#define ST_BH1(BW) do { gload_lds16(gB1 + ko, (BW) + (8 + w) * 1024); \
                        gload_lds16(gB1 + ko + 32, (BW) + (8 + w) * 1024 + 512); } while (0)

#define RD_AF(AR, qm) do { _Pragma("unroll") \
    for (int mi = 0; mi < 4; ++mi) { _Pragma("unroll") \
      for (int kt = 0; kt < 2; ++kt) \
        af[mi][kt] = *(const f16x8*)((AR) + (((qm) * 8 + wm * 4 + mi) * 2 + kt) * 512 + lane * 8); } } while (0)
#define RD_BF(BR, qn) do { _Pragma("unroll") \
    for (int nj = 0; nj < 2; ++nj) { _Pragma("unroll") \
      for (int kt = 0; kt < 2; ++kt) \
        bf[nj][kt] = *(const f16x8*)((BR) + (((qn) * 8 + wn * 2 + nj) * 2 + kt) * 512 + lane * 8); } } while (0)

#define MF16(q) do { __builtin_amdgcn_s_setprio(1); _Pragma("unroll") \
    for (int mi = 0; mi < 4; ++mi) { _Pragma("unroll") \
      for (int nj = 0; nj < 2; ++nj) { _Pragma("unroll") \
        for (int kt = 0; kt < 2; ++kt) \
          acc[q][mi][nj] = __builtin_amdgcn_mfma_f32_16x16x32_f16(af[mi][kt], bf[nj][kt], acc[q][mi][nj], 0, 0, 0); } } \
    __builtin_amdgcn_s_setprio(0); } while (0)

#define WV4_ asm volatile("s_waitcnt vmcnt(4)" ::: "memory")
#define WV2_ asm volatile("s_waitcnt vmcnt(2)" ::: "memory")
#define WV0_ asm volatile("s_waitcnt vmcnt(0)" ::: "memory")
#define BARR_ do { __builtin_amdgcn_s_barrier(); __builtin_amdgcn_sched_barrier(0); } while (0)

#define TILE(AR, BR, AW, BW) do {                                  \
    WV4_; BARR_; ST_AH0(AW); RD_AF(AR, 0); RD_BF(BR, 0); MF16(0);  \
    WV4_; BARR_; ST_BH0(BW); RD_BF(BR, 1); MF16(1);                \
    WV4_; BARR_; ST_BH1(BW); RD_AF(AR, 1); MF16(2);                \
          BARR_; ST_AH1(AW); RD_BF(BR, 0); MF16(3);                \
    ko += 64; } while (0)

#define TILE_LAST(AR, BR) do {                                     \
    WV4_; BARR_; RD_AF(AR, 0); RD_BF(BR, 0); MF16(0);              \
    WV2_; BARR_; RD_BF(BR, 1); MF16(1);                            \
    WV0_; BARR_; RD_AF(AR, 1); MF16(2);                            \
          BARR_; RD_BF(BR, 0); MF16(3); } while (0)

  // prologue: stage tile 0 fully (same half order), then uniform loop
  ST_AH0(As0); ST_BH0(Bs0); ST_BH1(Bs0); ST_AH1(As0);
  ko = 64;

  const int nt = K >> 6;            // 16
  for (int t = 0; t + 2 < nt; t += 2) {
    TILE(As0, Bs0, As1, Bs1);
    TILE(As1, Bs1, As0, Bs0);
  }
  TILE(As0, Bs0, As1, Bs1);         // tile nt-2 (stages tile nt-1)
  TILE_LAST(As1, Bs1);              // tile nt-1

#undef ST_AH0
#undef ST_AH1
#undef ST_BH0
#undef ST_BH1
#undef RD_AF
#undef RD_BF
#undef MF16
#undef WV4_
#undef WV2_
#undef WV0_
#undef BARR_
#undef TILE
#undef TILE_LAST

  // Epilogue. C/D layout (verified m89/m91): col = lane&15, row = quad*4 + reg.
  const int QM[4] = {0, 0, 1, 1};
  const int QN[4] = {0, 1, 1, 0};
  if (z < 2) {
    f16* C = (z == 0) ? Qf : Kn;
    const int ldc = 2048, halfw = 1024;
#pragma unroll
    for (int q = 0; q < 4; ++q) {
      const int rbase = m0 + QM[q] * 128 + wm * 64;
      const int cbase = n0 + QN[q] * 128 + wn * 32;
#pragma unroll
      for (int mi = 0; mi < 4; ++mi) {
        const int mg = rbase + mi * 16 + quad * 4;
        float sn[4], cn[4];
#pragma unroll
        for (int rr = 0; rr < 4; ++rr) {
          const int l = (mg + rr) >> 2;          // natural row = l*4 + b
          const float ang = 7.6699039394282066e-4f * (float)(l + 1);  // (pi/2)/2048*(l+1)
          __sincosf(ang, &sn[rr], &cn[rr]);
        }
#pragma unroll
        for (int nj = 0; nj < 2; ++nj) {
          const int ng = cbase + nj * 16 + l15;
          const float bc = bias[ng];
#pragma unroll
          for (int rr = 0; rr < 4; ++rr) {
            const float v = fmaxf(acc[q][mi][nj][rr] + bc, 0.f);
            C[(long)(mg + rr) * ldc + ng]         = (f16)(v * sn[rr]);
            C[(long)(mg + rr) * ldc + ng + halfw] = (f16)(v * cn[rr]);
          }
        }
      }
    }
  } else {
    f16* C = Vp;
    const int ldc = 1024;
#pragma unroll
    for (int q = 0; q < 4; ++q) {
      const int rbase = m0 + QM[q] * 128 + wm * 64;
      const int cbase = n0 + QN[q] * 128 + wn * 32;
#pragma unroll
      for (int mi = 0; mi < 4; ++mi) {
        const int mg = rbase + mi * 16 + quad * 4;
#pragma unroll
        for (int nj = 0; nj < 2; ++nj) {
          const int ng = cbase + nj * 16 + l15;
          const float bc = bias[ng];
#pragma unroll
          for (int rr = 0; rr < 4; ++rr)
            C[(long)(mg + rr) * ldc + ng] = (f16)(acc[q][mi][nj][rr] + bc);
        }
      }
    }
  }
}

// ---------------------------------------------------------------------------
// R7 core (verbatim): depth-2 counted-vmcnt 256x128xBK32, 8 waves, 96KB LDS.
// Used for kv and attn stages (their best measured config).
__device__ __forceinline__ void mm_core_kva(const f16* __restrict__ A, int lda,
                                            const f16* __restrict__ B, int ldb,
                                            int K, int m0, int n0,
                                            f16* As0, f16* Bs0, f16* As1, f16* Bs1,
                                            f16* As2, f16* Bs2, f16* As3, f16* Bs3,
                                            f32x4 (&acc)[4][4]) {
  const int tid  = threadIdx.x;
  const int lane = tid & 63;
  const int w    = tid >> 6;        // wave 0..7
  const int wm   = w >> 1, wn = w & 1;
  const int l15  = lane & 15;
  const int quad = lane >> 4;

  const f16* pa0 = A + (long)(m0 + w * 16 + l15) * lda + quad * 8;        // A block w
  const f16* pa1 = A + (long)(m0 + (8 + w) * 16 + l15) * lda + quad * 8;  // A block 8+w
  const f16* pb0 = B + (long)(n0 + w * 16 + l15) * ldb + quad * 8;        // B block w
  int koff = 0;

#define STAGE_(Ab, Bb) do {                        \
    gload_lds16(pa0 + koff, (Ab) + w * 512);       \
    gload_lds16(pa1 + koff, (Ab) + (8 + w) * 512); \
    gload_lds16(pb0 + koff, (Bb) + w * 512);       \
    koff += 32; } while (0)

#define COMPUTE_(Ab, Bb) do {                                                    \
    f16x8 af[4], bf[4];                                                          \
    _Pragma("unroll")                                                            \
    for (int i = 0; i < 4; ++i)                                                  \
      af[i] = *(const f16x8*)((Ab) + (wm * 4 + i) * 512 + lane * 8);             \
    _Pragma("unroll")                                                            \
    for (int j = 0; j < 4; ++j)                                                  \
      bf[j] = *(const f16x8*)((Bb) + (wn * 4 + j) * 512 + lane * 8);             \
    _Pragma("unroll")                                                            \
    for (int i = 0; i < 4; ++i)                                                  \
      _Pragma("unroll")                                                          \
      for (int j = 0; j < 4; ++j)                                                \
        acc[i][j] = __builtin_amdgcn_mfma_f32_16x16x32_f16(af[i], bf[j],         \
                                                           acc[i][j], 0, 0, 0); \
  } while (0)

#define WV3_ asm volatile("s_waitcnt vmcnt(3)" ::: "memory")
#define WV0_ asm volatile("s_waitcnt vmcnt(0)" ::: "memory")
#define BARR_ do { __builtin_amdgcn_s_barrier(); __builtin_amdgcn_sched_barrier(0); } while (0)

  // prologue: 2 stages in flight
  STAGE_(As0, Bs0);
  STAGE_(As1, Bs1);

  const int nt = K >> 5;            // 64 for K=2048; nt % 4 == 0
  for (int t = 0; t + 5 < nt; t += 4) {
    WV3_; BARR_; STAGE_(As2, Bs2); COMPUTE_(As0, Bs0);
    WV3_; BARR_; STAGE_(As3, Bs3); COMPUTE_(As1, Bs1);
    WV3_; BARR_; STAGE_(As0, Bs0); COMPUTE_(As2, Bs2);
    WV3_; BARR_; STAGE_(As1, Bs1); COMPUTE_(As3, Bs3);
  }
  // peeled final 4 sub-steps
  WV3_; BARR_; STAGE_(As2, Bs2); COMPUTE_(As0, Bs0);
  WV3_; BARR_; STAGE_(As3, Bs3); COMPUTE_(As1, Bs1);
  WV3_; BARR_; COMPUTE_(As2, Bs2);
  WV0_; BARR_; COMPUTE_(As3, Bs3);

#undef STAGE_
#undef COMPUTE_
#undef WV3_
#undef WV0_
#undef BARR_
}

#define GEMM_LDS                                   \
  __shared__ alignas(16) f16 As0[8192];            \
  __shared__ alignas(16) f16 Bs0[4096];            \
  __shared__ alignas(16) f16 As1[8192];            \
  __shared__ alignas(16) f16 Bs1[4096];            \
  __shared__ alignas(16) f16 As2[8192];            \
  __shared__ alignas(16) f16 Bs2[4096];            \
  __shared__ alignas(16) f16 As3[8192];            \
  __shared__ alignas(16) f16 Bs3[4096];

// ---------------------------------------------------------------------------
// Generic GEMM (kv and attn stages), 512 thr, BM=256/BN=128 (R7 verbatim).
// MODE 2: kv   -> f16 C = acc
// MODE 3: attn -> f32 C = acc * z[l*4+bz]
template<int MODE>
__launch_bounds__(512, 2)
__global__ void gemm_bt(const f16* __restrict__ A, int lda,
                        const f16* __restrict__ B, int ldb,
                        void* __restrict__ Cout, int K, int ldc,
                        const float* __restrict__ zvec,
                        long abatch, long bbatch, long cbatch)
{
  GEMM_LDS
  int bx, by, bz;
  xcd_swz(bx, by, bz);
  A += (long)bz * abatch;
  B += (long)bz * bbatch;
  const int m0 = by * 256;
  const int n0 = bx * 128;

  f32x4 acc[4][4] = {};
  mm_core_kva(A, lda, B, ldb, K, m0, n0,
              As0, Bs0, As1, Bs1, As2, Bs2, As3, Bs3, acc);

  const int tid  = threadIdx.x;
  const int lane = tid & 63;
  const int w    = tid >> 6;
  const int wm   = w >> 1, wn = w & 1;
  const int l15  = lane & 15;
  const int quad = lane >> 4;

  if constexpr (MODE == 2) {
    f16* C = (f16*)Cout + (long)bz * cbatch;
#pragma unroll
    for (int i = 0; i < 4; ++i) {
      const int mg = m0 + wm * 64 + i * 16 + quad * 4;
#pragma unroll
      for (int j = 0; j < 4; ++j) {
        const int ng = n0 + wn * 64 + j * 16 + l15;
#pragma unroll
        for (int rr = 0; rr < 4; ++rr)
          C[(long)(mg + rr) * ldc + ng] = (f16)acc[i][j][rr];
      }
    }
  } else {  // MODE 3: attn, f32 out, scale by z
    float* C = (float*)Cout + (long)bz * cbatch;
#pragma unroll
    for (int i = 0; i < 4; ++i) {
      const int mg = m0 + wm * 64 + i * 16 + quad * 4;
      float zr[4];
#pragma unroll
      for (int rr = 0; rr < 4; ++rr) zr[rr] = zvec[(long)(mg + rr) * 4 + bz];
#pragma unroll
      for (int j = 0; j < 4; ++j) {
        const int ng = n0 + wn * 64 + j * 16 + l15;
#pragma unroll
        for (int rr = 0; rr < 4; ++rr)
          C[(long)(mg + rr) * ldc + ng] = acc[i][j][rr] * zr[rr];
      }
    }
  }
}

// ---------------------------------------------------------------------------
// fp16 64x64 LDS-tiled transpose, K and V fused in one launch. If ks != null
// (alias-free big-ws path), K-blocks also accumulate ksum[b][d] via 4-lane
// shfl reduce of the 16 s-values each thread holds -> 64 atomicAdd/block
// (32 adds/address total across the grid). ks must be pre-zeroed.
// grid = (32, 32, 8): z<4 -> K batch z; z>=4 -> V batch z-4 (x<16 only).
__global__ void transpose_fused(const f16* __restrict__ Kn, f16* __restrict__ Kt,
                                const f16* __restrict__ Vp, f16* __restrict__ Vt,
                                float* __restrict__ ks) {
  __shared__ f16 tile[64 * 72];   // +8 halves pad (144B stride keeps 16B alignment)
  const int z = blockIdx.z;
  const f16* in;
  f16* out;
  long in_batch, out_batch;
  int ldin, ldout, b;
  if (z < 4) {
    in = Kn; out = Kt; in_batch = 2048; out_batch = 2048L * 2048;
    ldin = 8192; ldout = 2048; b = z;
  } else {
    if (blockIdx.x >= 16) return;   // V col dim is 1024 (uniform exit, pre-barrier)
    in = Vp; out = Vt; in_batch = 1024; out_batch = 1024L * 2048;
    ldin = 4096; ldout = 2048; b = z - 4;
  }
  in  += (long)b * in_batch;
  out += (long)b * out_batch;
  const int r0 = blockIdx.y * 64;
  const int c0 = blockIdx.x * 64;
  const int t  = threadIdx.x;
  {
    const int r = t >> 2, cs = (t & 3) * 16;
    const f16* src = in + (long)(r0 + r) * ldin + c0 + cs;
    f16x8 v0 = *(const f16x8*)(src);
    f16x8 v1 = *(const f16x8*)(src + 8);
    *(f16x8*)(tile + r * 72 + cs)     = v0;
    *(f16x8*)(tile + r * 72 + cs + 8) = v1;
  }
  __syncthreads();
  {
    const int c = t >> 2, rs = (t & 3) * 16;
    alignas(16) f16 tmp[16];
#pragma unroll
    for (int j = 0; j < 16; ++j) tmp[j] = tile[(rs + j) * 72 + c];
    f16* dst = out + (long)(c0 + c) * ldout + r0 + rs;
    *(f16x8*)(dst)     = *(const f16x8*)(tmp);
    *(f16x8*)(dst + 8) = *(const f16x8*)(tmp + 8);
    if (z < 4 && ks != nullptr) {
      // partial ksum over this block's 16 s-values for d = c0+c
      float s = 0.f;
#pragma unroll
      for (int j = 0; j < 16; ++j) s += (float)tmp[j];
      // threads 4c..4c+3 (aligned group of 4 in one wave) hold rs=0,16,32,48
      s += __shfl_down(s, 1, 4);
      s += __shfl_down(s, 2, 4);
      if ((t & 3) == 0) atomicAdd(&ks[(long)b * 2048 + c0 + c], s);
    }
  }
}

// ---------------------------------------------------------------------------
// k_sum[b][d] = sum_s K_t[b][d][s]  (fallback path: overwrite, no zeroing,
// runs after Kn is dead so ks@102MB aliasing is safe)
__global__ void ksum_kernel(const f16* __restrict__ Kt, float* __restrict__ ks) {
  const long row = blockIdx.x;
  const int t = threadIdx.x;
  f16x8 v = *(const f16x8*)(Kt + row * 2048 + t * 8);
  float s = 0.f;
#pragma unroll
  for (int j = 0; j < 8; ++j) s += (float)v[j];
#pragma unroll
  for (int off = 32; off > 0; off >>= 1) s += __shfl_down(s, off, 64);
  __shared__ float red[4];
  if ((t & 63) == 0) red[t >> 6] = s;
  __syncthreads();
  if (t == 0) ks[row] = red[0] + red[1] + red[2] + red[3];
}

// z[r=l*4+b] = 1 / max(sum_d Q_[r][d] * k_sum[b][d], eps)
__global__ void z_kernel(const f16* __restrict__ Qf, const float* __restrict__ ks,
                         float* __restrict__ zb) {
  const long r = blockIdx.x;
  const int t = threadIdx.x;
  const int b = (int)(r & 3);
  f16x8 q = *(const f16x8*)(Qf + r * 2048 + t * 8);
  const float* kp = ks + b * 2048 + t * 8;
  float s = 0.f;
#pragma unroll
  for (int j = 0; j < 8; ++j) s += (float)q[j] * kp[j];
#pragma unroll
  for (int off = 32; off > 0; off >>= 1) s += __shfl_down(s, off, 64);
  __shared__ float red[4];
  if ((t & 63) == 0) red[t >> 6] = s;
  __syncthreads();
  if (t == 0) zb[r] = 1.f / fmaxf(red[0] + red[1] + red[2] + red[3], 1e-6f);
}

// ---------------------------------------------------------------------------
extern "C" void kernel_launch(void* const* d_in, const int* in_sizes, int n_in,
                              void* d_out, int out_size, void* d_ws, size_t ws_size,
                              hipStream_t stream) {
  const float* query = (const float*)d_in[0];
  const float* key_  = (const float*)d_in[1];
  const float* value = (const float*)d_in[2];
  const float* Wq    = (const float*)d_in[3];
  const float* bq    = (const float*)d_in[4];
  const float* Wk    = (const float*)d_in[5];
  const float* bk    = (const float*)d_in[6];
  const float* Wv    = (const float*)d_in[7];
  const float* bv    = (const float*)d_in[8];

  char* ws = (char*)d_ws;
  const size_t MB = 1ull << 20;
  // Workspace layout (lifetime-based aliasing). ks/zb at [102,104) alias Kn
  // rows 1024-1027 -> writable only AFTER transpose. Big-ws path relocates
  // ks to ws+134MB (beyond all lifetimes, alias-free) to allow early zeroing
  // + in-transpose atomic accumulation (the R13 fold, fixed).
  f16* wq16 = (f16*)(ws + 0 * MB);    // 2 MB
  f16* wk16 = (f16*)(ws + 2 * MB);    // 2 MB
  f16* wv16 = (f16*)(ws + 4 * MB);    // 2 MB
  f16* q16  = (f16*)(ws + 6 * MB);    // 16 MB (dead after proj GEMMs)
  f16* k16  = (f16*)(ws + 22 * MB);   // 16 MB (dead after proj GEMMs)
  f16* v16  = (f16*)(ws + 38 * MB);   // 16 MB (dead after proj GEMMs)
  f16* Qf   = (f16*)(ws + 54 * MB);   // 32 MB  Q_ [l*4+b][2048]
  f16* Kn   = (f16*)(ws + 86 * MB);   // 32 MB  K_ natural [s*4+b][2048] (dead after transpose)
  f16* Vp   = (f16*)(ws + 118 * MB);  // 16 MB  V  natural [s*4+b][1024] (dead after transpose)
  f16* Kt   = (f16*)(ws + 6 * MB);    // 32 MB  K_t [b][d][s]   (aliases q16+k16)
  f16* Vt   = (f16*)(ws + 38 * MB);   // 16 MB  V_t [b][m][s]   (aliases v16)
  f16* kvb  = (f16*)(ws + 86 * MB);   // 16 MB  kv  [b][m][d]   (aliases Kn)
  float* zb = (float*)(ws + 103 * MB);  // 32 KB z[l*4+b]  (write AFTER transpose only)

  const bool big_ws = ws_size >= 135 * MB;
  float* ks = big_ws ? (float*)(ws + 134 * MB)   // alias-free home
                     : (float*)(ws + 102 * MB);  // fallback (post-transpose only)

  // 1) f32 -> f16 for all 6 tensors (one launch)
  cvt_all<<<dim3(9216, 1, 3), 256, 0, stream>>>(query, key_, value, Wq, Wk, Wv,
                                                q16, k16, v16, wq16, wk16, wv16);

  // 2) projections fused (M=8192, N=1024, K=1024; z selects Q/K/V); 384 blocks
  proj_gemm<<<dim3(4, 32, 3), 512, 0, stream>>>(q16, k16, v16, wq16, wk16, wv16,
                                                bq, bk, bv, Qf, Kn, Vp);

  // 3) transposes fused (+ in-transpose ksum on big-ws path)
  if (big_ws) {
    hipMemsetAsync(ks, 0, 8192 * sizeof(float), stream);  // stream-ordered zero
    transpose_fused<<<dim3(32, 32, 8), 256, 0, stream>>>(Kn, Kt, Vp, Vt, ks);
  } else {
    transpose_fused<<<dim3(32, 32, 8), 256, 0, stream>>>(Kn, Kt, Vp, Vt, nullptr);
    // 4a) k_sum separately (overwrite; safe after transpose)
    ksum_kernel<<<8192, 256, 0, stream>>>(Kt, ks);
  }

  // 4) z (after transpose: Kn dead, zb aliasing safe)
  z_kernel<<<8192, 256, 0, stream>>>(Qf, ks, zb);

  // 5) kv[b][m][d] = sum_s V_t[m][s] * K_t[d][s]  (M=1024, N=2048, K=2048); 256 blocks
  gemm_bt<2><<<dim3(16, 4, 4), 512, 0, stream>>>(Vt, 2048, Kt, 2048, kvb, 2048, 2048,
                                                 nullptr, 1024L * 2048, 2048L * 2048, 1024L * 2048);
  // 6) attn[l][b][m] = z * sum_d Q_[l][d] * kv[m][d]  (M=2048, N=1024, K=2048); 256 blocks
  gemm_bt<3><<<dim3(8, 8, 4), 512, 0, stream>>>(Qf, 8192, kvb, 2048, d_out, 2048, 4096,
                                                zb, 2048, 1024L * 2048, 1024);
}